// Round 1
// baseline (803.073 us; speedup 1.0000x reference)
//
#include <hip/hip_runtime.h>
#include <hip/hip_bf16.h>

// Problem constants (from reference):
//   H = 64, R = 32, feat_w: [N, 3H=192], radial: [E, R=32]
#define HH 64
#define RR 32
#define SILU_SCALE (1.0f / 0.6f)
#define INV_SQRT_3 0.57735026918962576f
#define INV_SQRT_H 0.125f   // 1/sqrt(64)

// ---------------------------------------------------------------------------
// Kernel 1: feat_w[n,k] = (silu(nf @ Wf1 + bf1) * SILU_SCALE) @ Wf2 + bf2
// One block (192 threads) processes nodes in a grid-stride loop.
// Weights staged in LDS (8KB + 24KB).
// ---------------------------------------------------------------------------
__global__ __launch_bounds__(192) void feat_kernel(
    const float* __restrict__ nf,
    const float* __restrict__ Wf1, const float* __restrict__ bf1,
    const float* __restrict__ Wf2, const float* __restrict__ bf2,
    float* __restrict__ fw, int N)
{
    __shared__ float sWf1[64 * 32];    // Wf1[i][j] at i*32+j
    __shared__ float sWf2[32 * 192];   // Wf2[j][k] at j*192+k
    __shared__ float sb1[32];
    __shared__ float sb2[192];
    __shared__ float snf[64];
    __shared__ float sh[32];

    const int tid = threadIdx.x;
    for (int i = tid; i < 64 * 32; i += 192) sWf1[i] = Wf1[i];
    for (int i = tid; i < 32 * 192; i += 192) sWf2[i] = Wf2[i];
    if (tid < 32) sb1[tid] = bf1[tid];
    sb2[tid] = bf2[tid];
    __syncthreads();

    for (int n = blockIdx.x; n < N; n += gridDim.x) {
        if (tid < 64) snf[tid] = nf[(size_t)n * 64 + tid];
        __syncthreads();
        if (tid < 32) {
            float a = sb1[tid];
            #pragma unroll
            for (int i = 0; i < 64; ++i) a = fmaf(snf[i], sWf1[i * 32 + tid], a);
            sh[tid] = a / (1.0f + __expf(-a)) * SILU_SCALE;
        }
        __syncthreads();
        float o = sb2[tid];
        #pragma unroll
        for (int j = 0; j < 32; ++j) o = fmaf(sh[j], sWf2[j * 192 + tid], o);
        fw[(size_t)n * 192 + tid] = o;
        __syncthreads();   // protect snf/sh before next iteration
    }
}

// ---------------------------------------------------------------------------
// Kernel 2: per-edge fused radial-projection + gather + scatter.
// One wave (64 lanes) per edge. Lane l owns feature index l:
//   w1 = radial_w[l], w2 = radial_w[64+l], w3 = radial_w[128+l]
// rad[32] is wave-uniform -> scalar loads; Wr columns live in 96 VGPRs,
// loaded once per wave (grid-stride amortizes).
// ---------------------------------------------------------------------------
__global__ __launch_bounds__(256) void edge_kernel(
    const float* __restrict__ vf,     // [N,3,64]
    const int*   __restrict__ ei,     // [2,E]
    const float* __restrict__ rad,    // [E,32]
    const float* __restrict__ ev,     // [E,3]
    const float* __restrict__ Wr,     // [32,192]
    const float* __restrict__ br,     // [192]
    const float* __restrict__ fw,     // [N,192]
    float* __restrict__ out_s,        // [N,64]
    float* __restrict__ out_v,        // [N,3,64]
    int E)
{
    const int lane = threadIdx.x & 63;
    const int wid  = __builtin_amdgcn_readfirstlane((int)(threadIdx.x >> 6));
    const int wavesPerBlock = blockDim.x >> 6;
    const int totalWaves = gridDim.x * wavesPerBlock;
    int w = blockIdx.x * wavesPerBlock + wid;

    // Per-lane Wr columns (persist across the edge loop).
    float c1[RR], c2[RR], c3[RR];
    #pragma unroll
    for (int r = 0; r < RR; ++r) {
        c1[r] = Wr[r * 192 + lane];
        c2[r] = Wr[r * 192 + 64 + lane];
        c3[r] = Wr[r * 192 + 128 + lane];
    }
    const float b1 = br[lane], b2 = br[64 + lane], b3 = br[128 + lane];

    for (int e = w; e < E; e += totalWaves) {
        const int eu  = __builtin_amdgcn_readfirstlane(e);
        const int src = ei[eu];
        const int tgt = ei[E + eu];

        // radial projection for this lane's 3 output features
        const float* rp = rad + (size_t)eu * RR;
        float w1 = b1, w2 = b2, w3 = b3;
        #pragma unroll
        for (int r = 0; r < RR; ++r) {
            const float rv = rp[r];             // wave-uniform -> s_load
            w1 = fmaf(rv, c1[r], w1);
            w2 = fmaf(rv, c2[r], w2);
            w3 = fmaf(rv, c3[r], w3);
        }

        const float evx = ev[eu * 3 + 0];
        const float evy = ev[eu * 3 + 1];
        const float evz = ev[eu * 3 + 2];

        const float* fwp = fw + (size_t)src * 192;
        const float cc1 = fwp[lane]       * w1 * INV_SQRT_3;
        const float cc2 = fwp[64 + lane]  * w2 * INV_SQRT_3;
        const float cc3 = fwp[128 + lane] * w3 * INV_SQRT_3;

        const float* vp = vf + (size_t)src * 192;
        const float vx = vp[lane];
        const float vy = vp[64 + lane];
        const float vz = vp[128 + lane];

        unsafeAtomicAdd(&out_s[(size_t)tgt * 64 + lane], cc3);
        unsafeAtomicAdd(&out_v[(size_t)tgt * 192 + lane],       (cc1 * vx + cc2 * evx) * INV_SQRT_H);
        unsafeAtomicAdd(&out_v[(size_t)tgt * 192 + 64 + lane],  (cc1 * vy + cc2 * evy) * INV_SQRT_H);
        unsafeAtomicAdd(&out_v[(size_t)tgt * 192 + 128 + lane], (cc1 * vz + cc2 * evz) * INV_SQRT_H);
    }
}

extern "C" void kernel_launch(void* const* d_in, const int* in_sizes, int n_in,
                              void* d_out, int out_size, void* d_ws, size_t ws_size,
                              hipStream_t stream) {
    const float* nf  = (const float*)d_in[0];   // [N,64]
    const float* vf  = (const float*)d_in[1];   // [N,3,64]
    const int*   ei  = (const int*)  d_in[2];   // [2,E]
    const float* rad = (const float*)d_in[3];   // [E,32]
    const float* ev  = (const float*)d_in[4];   // [E,3]
    const float* Wf1 = (const float*)d_in[5];
    const float* bf1 = (const float*)d_in[6];
    const float* Wf2 = (const float*)d_in[7];
    const float* bf2 = (const float*)d_in[8];
    const float* Wr  = (const float*)d_in[9];
    const float* br  = (const float*)d_in[10];

    const int N = in_sizes[0] / HH;
    const int E = in_sizes[2] / 2;

    float* fw    = (float*)d_ws;                 // [N,192] scratch
    float* out_s = (float*)d_out;                // [N,64]
    float* out_v = out_s + (size_t)N * HH;       // [N,3,64]

    // Outputs are accumulated atomically -> must start from zero every call.
    hipMemsetAsync(d_out, 0, (size_t)out_size * sizeof(float), stream);

    feat_kernel<<<1024, 192, 0, stream>>>(nf, Wf1, bf1, Wf2, bf2, fw, N);

    edge_kernel<<<2048, 256, 0, stream>>>(vf, ei, rad, ev, Wr, br, fw,
                                          out_s, out_v, E);
}

// Round 2
// 512.524 us; speedup vs baseline: 1.5669x; 1.5669x over previous
//
#include <hip/hip_runtime.h>
#include <hip/hip_bf16.h>

#define HH 64
#define RR 32
#define SILU_SCALE (1.0f / 0.6f)
#define INV_SQRT_3 0.57735026918962576f
#define INV_SQRT_H 0.125f   // 1/sqrt(64)
#define SB 256              // scan block size

// ---------------------------------------------------------------------------
// Kernel 1: feat_w[n,k] = (silu(nf @ Wf1 + bf1) * SILU_SCALE) @ Wf2 + bf2
// ---------------------------------------------------------------------------
__global__ __launch_bounds__(192) void feat_kernel(
    const float* __restrict__ nf,
    const float* __restrict__ Wf1, const float* __restrict__ bf1,
    const float* __restrict__ Wf2, const float* __restrict__ bf2,
    float* __restrict__ fw, int N)
{
    __shared__ float sWf1[64 * 32];
    __shared__ float sWf2[32 * 192];
    __shared__ float sb1[32];
    __shared__ float sb2[192];
    __shared__ float snf[64];
    __shared__ float sh[32];

    const int tid = threadIdx.x;
    for (int i = tid; i < 64 * 32; i += 192) sWf1[i] = Wf1[i];
    for (int i = tid; i < 32 * 192; i += 192) sWf2[i] = Wf2[i];
    if (tid < 32) sb1[tid] = bf1[tid];
    sb2[tid] = bf2[tid];
    __syncthreads();

    for (int n = blockIdx.x; n < N; n += gridDim.x) {
        if (tid < 64) snf[tid] = nf[(size_t)n * 64 + tid];
        __syncthreads();
        if (tid < 32) {
            float a = sb1[tid];
            #pragma unroll
            for (int i = 0; i < 64; ++i) a = fmaf(snf[i], sWf1[i * 32 + tid], a);
            sh[tid] = a / (1.0f + __expf(-a)) * SILU_SCALE;
        }
        __syncthreads();
        float o = sb2[tid];
        #pragma unroll
        for (int j = 0; j < 32; ++j) o = fmaf(sh[j], sWf2[j * 192 + tid], o);
        fw[(size_t)n * 192 + tid] = o;
        __syncthreads();
    }
}

// ---------------------------------------------------------------------------
// Counting sort of edges by target: hist -> scan (3 small kernels) -> fill
// ---------------------------------------------------------------------------
__global__ __launch_bounds__(256) void hist_kernel(
    const int* __restrict__ ei, int* __restrict__ cnt, int E)
{
    for (int e = blockIdx.x * blockDim.x + threadIdx.x; e < E;
         e += gridDim.x * blockDim.x)
        atomicAdd(&cnt[ei[E + e]], 1);
}

__global__ __launch_bounds__(SB) void scanA_kernel(
    const int* __restrict__ cnt, int* __restrict__ ptr,
    int* __restrict__ bsum, int N)
{
    __shared__ int s[SB];
    const int t = threadIdx.x;
    const int i = blockIdx.x * SB + t;
    const int v = (i < N) ? cnt[i] : 0;
    s[t] = v; __syncthreads();
    for (int off = 1; off < SB; off <<= 1) {
        int x = (t >= off) ? s[t - off] : 0;
        __syncthreads();
        s[t] += x;
        __syncthreads();
    }
    if (i < N) ptr[i] = s[t] - v;          // block-local exclusive
    if (t == SB - 1) bsum[blockIdx.x] = s[t];
}

__global__ __launch_bounds__(SB) void scanB_kernel(
    int* __restrict__ bsum, int nb, int* __restrict__ ptr, int N, int E)
{
    __shared__ int s[SB];
    const int t = threadIdx.x;
    int carry = 0;
    for (int base = 0; base < nb; base += SB) {
        const int i = base + t;
        const int v = (i < nb) ? bsum[i] : 0;
        s[t] = v; __syncthreads();
        for (int off = 1; off < SB; off <<= 1) {
            int x = (t >= off) ? s[t - off] : 0;
            __syncthreads();
            s[t] += x;
            __syncthreads();
        }
        const int total = s[SB - 1];
        if (i < nb) bsum[i] = carry + s[t] - v;   // exclusive across blocks
        carry += total;
        __syncthreads();
    }
    if (t == 0) ptr[N] = E;
}

__global__ __launch_bounds__(SB) void scanC_kernel(
    int* __restrict__ ptr, int* __restrict__ head,
    const int* __restrict__ bsum, int N)
{
    const int i = blockIdx.x * SB + threadIdx.x;
    if (i < N) {
        const int p = ptr[i] + bsum[blockIdx.x];
        ptr[i] = p;
        head[i] = p;
    }
}

__global__ __launch_bounds__(256) void fill_kernel(
    const int* __restrict__ ei, int* __restrict__ head,
    int2* __restrict__ pairs, int E)
{
    for (int e = blockIdx.x * blockDim.x + threadIdx.x; e < E;
         e += gridDim.x * blockDim.x) {
        const int t = ei[E + e];
        const int pos = atomicAdd(&head[t], 1);
        pairs[pos] = make_int2(e, ei[e]);
    }
}

// ---------------------------------------------------------------------------
// Aggregation: one wave per node, accumulate in registers, plain stores.
// Lane l owns feature l (and 64+l, 128+l of the 3H projection).
// Wr columns pinned in VGPRs via empty-asm (compiler must not rematerialize).
// ---------------------------------------------------------------------------
__global__ __launch_bounds__(256) void agg_kernel(
    const float* __restrict__ vf,     // [N,3,64]
    const float* __restrict__ rad,    // [E,32]
    const float* __restrict__ ev,     // [E,3]
    const float* __restrict__ Wr,     // [32,192]
    const float* __restrict__ br,     // [192]
    const float* __restrict__ fw,     // [N,192]
    const int*   __restrict__ ptr,    // [N+1]
    const int2*  __restrict__ pairs,  // [E] (edge, src)
    float* __restrict__ out_s,        // [N,64]
    float* __restrict__ out_v,        // [N,3,64]
    int N)
{
    const int lane = threadIdx.x & 63;
    const int wid  = __builtin_amdgcn_readfirstlane((int)(threadIdx.x >> 6));
    const int wavesPerBlock = blockDim.x >> 6;
    const int totalWaves = gridDim.x * wavesPerBlock;
    const int gw = blockIdx.x * wavesPerBlock + wid;

    float c1[RR], c2[RR], c3[RR];
    #pragma unroll
    for (int r = 0; r < RR; ++r) {
        c1[r] = Wr[r * 192 + lane];
        c2[r] = Wr[r * 192 + 64 + lane];
        c3[r] = Wr[r * 192 + 128 + lane];
    }
    // Pin to VGPRs: make values opaque so the compiler cannot re-load Wr
    // inside the edge loop (round-1 failure mode: VGPR_Count=60 => remat).
    #pragma unroll
    for (int r = 0; r < RR; ++r) {
        asm volatile("" : "+v"(c1[r]), "+v"(c2[r]), "+v"(c3[r]));
    }
    const float b1 = br[lane], b2 = br[64 + lane], b3 = br[128 + lane];

    for (int n = gw; n < N; n += totalWaves) {
        const int nu    = __builtin_amdgcn_readfirstlane(n);
        const int start = ptr[nu];
        const int end   = ptr[nu + 1];

        float as = 0.f, ax = 0.f, ay = 0.f, az = 0.f;

        for (int base = start; base < end; base += 64) {
            const int idx = base + lane;
            int2 ep = make_int2(0, 0);
            if (idx < end) ep = pairs[idx];
            const int m = min(64, end - base);

            for (int j = 0; j < m; ++j) {
                const int e = __builtin_amdgcn_readlane(ep.x, j);
                const int s = __builtin_amdgcn_readlane(ep.y, j);

                // radial projection for this lane's 3 output features
                const float* rp = rad + (size_t)e * RR;
                float w1 = b1, w2 = b2, w3 = b3;
                #pragma unroll
                for (int r = 0; r < RR; ++r) {
                    const float rv = rp[r];          // scalar (e uniform)
                    w1 = fmaf(rv, c1[r], w1);
                    w2 = fmaf(rv, c2[r], w2);
                    w3 = fmaf(rv, c3[r], w3);
                }

                const float evx = ev[e * 3 + 0];
                const float evy = ev[e * 3 + 1];
                const float evz = ev[e * 3 + 2];

                const float* fp = fw + (size_t)s * 192;
                const float cc1 = fp[lane]       * w1 * INV_SQRT_3;
                const float cc2 = fp[64 + lane]  * w2 * INV_SQRT_3;
                const float cc3 = fp[128 + lane] * w3 * INV_SQRT_3;

                const float* vp = vf + (size_t)s * 192;
                as += cc3;
                ax = fmaf(cc1, vp[lane],        fmaf(cc2, evx, ax));
                ay = fmaf(cc1, vp[64 + lane],   fmaf(cc2, evy, ay));
                az = fmaf(cc1, vp[128 + lane],  fmaf(cc2, evz, az));
            }
        }

        out_s[(size_t)nu * 64 + lane]        = as;
        out_v[(size_t)nu * 192 + lane]       = ax * INV_SQRT_H;
        out_v[(size_t)nu * 192 + 64 + lane]  = ay * INV_SQRT_H;
        out_v[(size_t)nu * 192 + 128 + lane] = az * INV_SQRT_H;
    }
}

// ---------------------------------------------------------------------------
// Fallback (atomic scatter) in case ws_size can't hold the CSR scratch.
// ---------------------------------------------------------------------------
__global__ __launch_bounds__(256) void edge_kernel_atomic(
    const float* __restrict__ vf, const int* __restrict__ ei,
    const float* __restrict__ rad, const float* __restrict__ ev,
    const float* __restrict__ Wr, const float* __restrict__ br,
    const float* __restrict__ fw,
    float* __restrict__ out_s, float* __restrict__ out_v, int E)
{
    const int lane = threadIdx.x & 63;
    const int wid  = __builtin_amdgcn_readfirstlane((int)(threadIdx.x >> 6));
    const int wavesPerBlock = blockDim.x >> 6;
    const int totalWaves = gridDim.x * wavesPerBlock;
    const int w0 = blockIdx.x * wavesPerBlock + wid;

    float c1[RR], c2[RR], c3[RR];
    #pragma unroll
    for (int r = 0; r < RR; ++r) {
        c1[r] = Wr[r * 192 + lane];
        c2[r] = Wr[r * 192 + 64 + lane];
        c3[r] = Wr[r * 192 + 128 + lane];
    }
    #pragma unroll
    for (int r = 0; r < RR; ++r) {
        asm volatile("" : "+v"(c1[r]), "+v"(c2[r]), "+v"(c3[r]));
    }
    const float b1 = br[lane], b2 = br[64 + lane], b3 = br[128 + lane];

    for (int e = w0; e < E; e += totalWaves) {
        const int eu  = __builtin_amdgcn_readfirstlane(e);
        const int src = ei[eu];
        const int tgt = ei[E + eu];

        const float* rp = rad + (size_t)eu * RR;
        float w1 = b1, w2 = b2, w3 = b3;
        #pragma unroll
        for (int r = 0; r < RR; ++r) {
            const float rv = rp[r];
            w1 = fmaf(rv, c1[r], w1);
            w2 = fmaf(rv, c2[r], w2);
            w3 = fmaf(rv, c3[r], w3);
        }

        const float evx = ev[eu * 3 + 0];
        const float evy = ev[eu * 3 + 1];
        const float evz = ev[eu * 3 + 2];

        const float* fp = fw + (size_t)src * 192;
        const float cc1 = fp[lane]       * w1 * INV_SQRT_3;
        const float cc2 = fp[64 + lane]  * w2 * INV_SQRT_3;
        const float cc3 = fp[128 + lane] * w3 * INV_SQRT_3;

        const float* vp = vf + (size_t)src * 192;
        unsafeAtomicAdd(&out_s[(size_t)tgt * 64 + lane], cc3);
        unsafeAtomicAdd(&out_v[(size_t)tgt * 192 + lane],
                        (cc1 * vp[lane] + cc2 * evx) * INV_SQRT_H);
        unsafeAtomicAdd(&out_v[(size_t)tgt * 192 + 64 + lane],
                        (cc1 * vp[64 + lane] + cc2 * evy) * INV_SQRT_H);
        unsafeAtomicAdd(&out_v[(size_t)tgt * 192 + 128 + lane],
                        (cc1 * vp[128 + lane] + cc2 * evz) * INV_SQRT_H);
    }
}

extern "C" void kernel_launch(void* const* d_in, const int* in_sizes, int n_in,
                              void* d_out, int out_size, void* d_ws, size_t ws_size,
                              hipStream_t stream) {
    const float* nf  = (const float*)d_in[0];
    const float* vf  = (const float*)d_in[1];
    const int*   ei  = (const int*)  d_in[2];
    const float* rad = (const float*)d_in[3];
    const float* ev  = (const float*)d_in[4];
    const float* Wf1 = (const float*)d_in[5];
    const float* bf1 = (const float*)d_in[6];
    const float* Wf2 = (const float*)d_in[7];
    const float* bf2 = (const float*)d_in[8];
    const float* Wr  = (const float*)d_in[9];
    const float* br  = (const float*)d_in[10];

    const int N = in_sizes[0] / HH;
    const int E = in_sizes[2] / 2;
    const int nb = (N + SB - 1) / SB;

    float* out_s = (float*)d_out;                // [N,64]
    float* out_v = out_s + (size_t)N * HH;       // [N,3,64]

    // ws layout
    char* ws = (char*)d_ws;
    size_t off = 0;
    float* fw = (float*)(ws + off);  off += (size_t)N * 192 * 4;
    int* cnt  = (int*)(ws + off);    off += (size_t)N * 4;
    int* ptr  = (int*)(ws + off);    off += (size_t)(N + 1) * 4;
    int* head = (int*)(ws + off);    off += (size_t)N * 4;
    int* bsum = (int*)(ws + off);    off += (size_t)nb * 4;
    off = (off + 15) & ~(size_t)15;
    int2* pairs = (int2*)(ws + off); off += (size_t)E * 8;

    feat_kernel<<<1024, 192, 0, stream>>>(nf, Wf1, bf1, Wf2, bf2, fw, N);

    if (off <= ws_size) {
        // --- CSR build ---
        hipMemsetAsync(cnt, 0, (size_t)N * 4, stream);
        hist_kernel<<<1024, 256, 0, stream>>>(ei, cnt, E);
        scanA_kernel<<<nb, SB, 0, stream>>>(cnt, ptr, bsum, N);
        scanB_kernel<<<1, SB, 0, stream>>>(bsum, nb, ptr, N, E);
        scanC_kernel<<<nb, SB, 0, stream>>>(ptr, head, bsum, N);
        fill_kernel<<<1024, 256, 0, stream>>>(ei, head, pairs, E);

        // --- atomic-free aggregation, writes every output element ---
        agg_kernel<<<2048, 256, 0, stream>>>(vf, rad, ev, Wr, br, fw,
                                             ptr, pairs, out_s, out_v, N);
    } else {
        hipMemsetAsync(d_out, 0, (size_t)out_size * sizeof(float), stream);
        edge_kernel_atomic<<<2048, 256, 0, stream>>>(vf, ei, rad, ev, Wr, br,
                                                     fw, out_s, out_v, E);
    }
}

// Round 3
// 498.159 us; speedup vs baseline: 1.6121x; 1.0288x over previous
//
#include <hip/hip_runtime.h>
#include <hip/hip_bf16.h>

#define HH 64
#define RR 32
#define SILU_SCALE (1.0f / 0.6f)
#define INV_SQRT_3 0.57735026918962576f
#define INV_SQRT_H 0.125f   // 1/sqrt(64)
#define SB 256              // scan block size
#define EPB 128             // edges per block in fused agg

typedef __attribute__((ext_vector_type(8))) short short8;
typedef __attribute__((ext_vector_type(4))) float f32x4;

// ---------------------------------------------------------------------------
// Kernel 1: feat_w[n,k] = (silu(nf @ Wf1 + bf1) * SILU_SCALE) @ Wf2 + bf2
// ---------------------------------------------------------------------------
__global__ __launch_bounds__(192) void feat_kernel(
    const float* __restrict__ nf,
    const float* __restrict__ Wf1, const float* __restrict__ bf1,
    const float* __restrict__ Wf2, const float* __restrict__ bf2,
    float* __restrict__ fw, int N)
{
    __shared__ float sWf1[64 * 32];
    __shared__ float sWf2[32 * 192];
    __shared__ float sb1[32];
    __shared__ float sb2[192];
    __shared__ float snf[64];
    __shared__ float sh[32];

    const int tid = threadIdx.x;
    for (int i = tid; i < 64 * 32; i += 192) sWf1[i] = Wf1[i];
    for (int i = tid; i < 32 * 192; i += 192) sWf2[i] = Wf2[i];
    if (tid < 32) sb1[tid] = bf1[tid];
    sb2[tid] = bf2[tid];
    __syncthreads();

    for (int n = blockIdx.x; n < N; n += gridDim.x) {
        if (tid < 64) snf[tid] = nf[(size_t)n * 64 + tid];
        __syncthreads();
        if (tid < 32) {
            float a = sb1[tid];
            #pragma unroll
            for (int i = 0; i < 64; ++i) a = fmaf(snf[i], sWf1[i * 32 + tid], a);
            sh[tid] = a / (1.0f + __expf(-a)) * SILU_SCALE;
        }
        __syncthreads();
        float o = sb2[tid];
        #pragma unroll
        for (int j = 0; j < 32; ++j) o = fmaf(sh[j], sWf2[j * 192 + tid], o);
        fw[(size_t)n * 192 + tid] = o;
        __syncthreads();
    }
}

// ---------------------------------------------------------------------------
// Counting sort of edges by target: hist -> scan -> fill
// ---------------------------------------------------------------------------
__global__ __launch_bounds__(256) void hist_kernel(
    const int* __restrict__ ei, int* __restrict__ cnt, int E)
{
    for (int e = blockIdx.x * blockDim.x + threadIdx.x; e < E;
         e += gridDim.x * blockDim.x)
        atomicAdd(&cnt[ei[E + e]], 1);
}

__global__ __launch_bounds__(SB) void scanA_kernel(
    const int* __restrict__ cnt, int* __restrict__ ptr,
    int* __restrict__ bsum, int N)
{
    __shared__ int s[SB];
    const int t = threadIdx.x;
    const int i = blockIdx.x * SB + t;
    const int v = (i < N) ? cnt[i] : 0;
    s[t] = v; __syncthreads();
    for (int off = 1; off < SB; off <<= 1) {
        int x = (t >= off) ? s[t - off] : 0;
        __syncthreads();
        s[t] += x;
        __syncthreads();
    }
    if (i < N) ptr[i] = s[t] - v;
    if (t == SB - 1) bsum[blockIdx.x] = s[t];
}

__global__ __launch_bounds__(SB) void scanB_kernel(
    int* __restrict__ bsum, int nb, int* __restrict__ ptr, int N, int E)
{
    __shared__ int s[SB];
    const int t = threadIdx.x;
    int carry = 0;
    for (int base = 0; base < nb; base += SB) {
        const int i = base + t;
        const int v = (i < nb) ? bsum[i] : 0;
        s[t] = v; __syncthreads();
        for (int off = 1; off < SB; off <<= 1) {
            int x = (t >= off) ? s[t - off] : 0;
            __syncthreads();
            s[t] += x;
            __syncthreads();
        }
        const int total = s[SB - 1];
        if (i < nb) bsum[i] = carry + s[t] - v;
        carry += total;
        __syncthreads();
    }
    if (t == 0) ptr[N] = E;
}

__global__ __launch_bounds__(SB) void scanC_kernel(
    int* __restrict__ ptr, int* __restrict__ head,
    const int* __restrict__ bsum, int N)
{
    const int i = blockIdx.x * SB + threadIdx.x;
    if (i < N) {
        const int p = ptr[i] + bsum[blockIdx.x];
        ptr[i] = p;
        head[i] = p;
    }
}

__global__ __launch_bounds__(256) void fill_kernel(
    const int* __restrict__ ei, int* __restrict__ head,
    int2* __restrict__ pairs, int* __restrict__ tgtc, int E)
{
    for (int e = blockIdx.x * blockDim.x + threadIdx.x; e < E;
         e += gridDim.x * blockDim.x) {
        const int t = ei[E + e];
        const int pos = atomicAdd(&head[t], 1);
        pairs[pos] = make_int2(e, ei[e]);
        tgtc[pos] = t;
    }
}

// ---------------------------------------------------------------------------
// Fused MFMA radial-projection + gather + segmented flush.
// Block = 256 threads (4 waves) handles EPB=128 CSR-consecutive edges.
//   phase 0: edge ids / src / tgt -> LDS; Wr^T -> LDS bf16 [192][40]
//   phase 1: gather rad rows -> LDS bf16 [128][40]
//   phase 2: MFMA P = rad @ Wr  ([128][192] bf16 in LDS, 400B rows, swizzled)
//   phase 3: per-wave serial sweep over its 32 CSR slots; accumulate per
//            target run in registers; atomic flush at run boundaries.
// LDS total ~78.4 KB -> 2 blocks/CU.
// ---------------------------------------------------------------------------
__global__ __launch_bounds__(256) void agg_mfma_kernel(
    const float* __restrict__ vf,     // [N,3,64]
    const float* __restrict__ rad,    // [E,32]
    const float* __restrict__ ev,     // [E,3]
    const float* __restrict__ Wr,     // [32,192]
    const float* __restrict__ br,     // [192]
    const float* __restrict__ fw,     // [N,192]
    const int2* __restrict__ pairs,   // [E] (edge, src) CSR-sorted by tgt
    const int*  __restrict__ tgtc,    // [E] tgt per CSR slot
    float* __restrict__ out_s,        // [N,64]
    float* __restrict__ out_v,        // [N,3,64]
    int E)
{
    __shared__ __align__(16) ushort Al[EPB * 40];    // rad bf16, 80B rows
    __shared__ __align__(16) ushort Bl[192 * 40];    // Wr^T bf16, 80B rows
    __shared__ __align__(16) ushort Pl[EPB * 200];   // P bf16, 400B rows
    __shared__ int eid_l[EPB];
    __shared__ int sid_l[EPB];
    __shared__ int tgt_l[EPB + 1];

    const int tid = threadIdx.x;
    const int b0 = blockIdx.x * EPB;
    const int nloc = min(EPB, E - b0);

    // ---- phase 0: ids + Wr^T staging ----
    if (tid < EPB) {
        int2 p = make_int2(0, 0);
        int t = -1;
        if (tid < nloc) { p = pairs[b0 + tid]; t = tgtc[b0 + tid]; }
        eid_l[tid] = p.x; sid_l[tid] = p.y; tgt_l[tid] = t;
    }
    if (tid == 0) tgt_l[EPB] = -1;
    if (tid < 192) {
        __align__(16) ushort tmp[32];
        #pragma unroll
        for (int k = 0; k < 32; ++k) {
            __hip_bfloat16 h = __float2bfloat16(Wr[k * 192 + tid]);
            tmp[k] = *(ushort*)&h;
        }
        #pragma unroll
        for (int c = 0; c < 4; ++c)
            *(short8*)&Bl[tid * 40 + c * 8] = *(short8*)&tmp[c * 8];
    }
    __syncthreads();

    // ---- phase 1: rad gather -> Al (2 threads per edge, 16 floats each) ----
    {
        const int il = tid >> 1;
        const int ks = (tid & 1) * 16;
        const int e = eid_l[il];
        const float* rp = rad + (size_t)e * RR + ks;
        __align__(16) ushort tmp[16];
        #pragma unroll
        for (int k = 0; k < 16; ++k) {
            __hip_bfloat16 h = __float2bfloat16(rp[k]);
            tmp[k] = *(ushort*)&h;
        }
        *(short8*)&Al[il * 40 + ks]     = *(short8*)&tmp[0];
        *(short8*)&Al[il * 40 + ks + 8] = *(short8*)&tmp[8];
    }
    __syncthreads();

    const int lane = tid & 63;
    const int w = tid >> 6;             // wave id 0..3

    // ---- phase 2: MFMA  P[128][192] = A[128][32] @ Wr[32][192] ----
    {
        const int r0 = w * 32;                // this wave's 32 rows
        const int kk = (lane >> 4) * 8;       // k offset (bf16 elems)
        const int mr = lane & 15;
        short8 a0 = *(const short8*)&Al[(r0 + mr) * 40 + kk];
        short8 a1 = *(const short8*)&Al[(r0 + 16 + mr) * 40 + kk];
        #pragma unroll
        for (int nt = 0; nt < 12; ++nt) {
            short8 b = *(const short8*)&Bl[(nt * 16 + mr) * 40 + kk];
            f32x4 c0 = {0.f, 0.f, 0.f, 0.f};
            f32x4 c1 = {0.f, 0.f, 0.f, 0.f};
            c0 = __builtin_amdgcn_mfma_f32_16x16x32_bf16(a0, b, c0, 0, 0, 0);
            c1 = __builtin_amdgcn_mfma_f32_16x16x32_bf16(a1, b, c1, 0, 0, 0);
            const int col2 = (nt * 16 + mr) * 2;  // byte offset of column
            #pragma unroll
            for (int r = 0; r < 4; ++r) {
                const int row0 = r0 + (lane >> 4) * 4 + r;   // C: row=(lane>>4)*4+reg
                const int row1 = row0 + 16;
                __hip_bfloat16 h0 = __float2bfloat16(c0[r]);
                __hip_bfloat16 h1 = __float2bfloat16(c1[r]);
                *(ushort*)((char*)Pl + row0 * 400 + (col2 ^ ((row0 & 12) << 3))) = *(ushort*)&h0;
                *(ushort*)((char*)Pl + row1 * 400 + (col2 ^ ((row1 & 12) << 3))) = *(ushort*)&h1;
            }
        }
    }
    __syncthreads();

    // ---- phase 3: segmented elementwise + flush ----
    const float brl1 = br[lane];
    const float brl2 = br[64 + lane];
    const float brl3 = br[128 + lane];

    const int i0 = w * 32;
    const int i1 = min(i0 + 32, nloc);
    float as = 0.f, ax = 0.f, ay = 0.f, az = 0.f;

    for (int i = i0; i < i1; ++i) {
        const int e = __builtin_amdgcn_readfirstlane(eid_l[i]);
        const int s = __builtin_amdgcn_readfirstlane(sid_l[i]);
        const int t = __builtin_amdgcn_readfirstlane(tgt_l[i]);
        const int tn = __builtin_amdgcn_readfirstlane(tgt_l[i + 1]);

        const int swz = (i & 12) << 3;
        const char* prow = (const char*)Pl + i * 400;
        ushort u1 = *(const ushort*)(prow + ((lane * 2) ^ swz));
        ushort u2 = *(const ushort*)(prow + (((64 + lane) * 2) ^ swz));
        ushort u3 = *(const ushort*)(prow + (((128 + lane) * 2) ^ swz));
        const float p1 = __bfloat162float(*(__hip_bfloat16*)&u1) + brl1;
        const float p2 = __bfloat162float(*(__hip_bfloat16*)&u2) + brl2;
        const float p3 = __bfloat162float(*(__hip_bfloat16*)&u3) + brl3;

        const float* fp = fw + (size_t)s * 192;
        const float* vp = vf + (size_t)s * 192;
        const float f1 = fp[lane], f2 = fp[64 + lane], f3 = fp[128 + lane];
        const float v1 = vp[lane], v2 = vp[64 + lane], v3 = vp[128 + lane];
        const float evx = ev[3 * e + 0];
        const float evy = ev[3 * e + 1];
        const float evz = ev[3 * e + 2];

        const float cc1 = f1 * p1 * INV_SQRT_3;
        const float cc2 = f2 * p2 * INV_SQRT_3;
        const float cc3 = f3 * p3 * INV_SQRT_3;

        as += cc3;
        ax = fmaf(cc1, v1, fmaf(cc2, evx, ax));
        ay = fmaf(cc1, v2, fmaf(cc2, evy, ay));
        az = fmaf(cc1, v3, fmaf(cc2, evz, az));

        if (i == i1 - 1 || tn != t) {
            unsafeAtomicAdd(&out_s[(size_t)t * 64 + lane], as);
            unsafeAtomicAdd(&out_v[(size_t)t * 192 + lane],       ax * INV_SQRT_H);
            unsafeAtomicAdd(&out_v[(size_t)t * 192 + 64 + lane],  ay * INV_SQRT_H);
            unsafeAtomicAdd(&out_v[(size_t)t * 192 + 128 + lane], az * INV_SQRT_H);
            as = ax = ay = az = 0.f;
        }
    }
}

// ---------------------------------------------------------------------------
// Fallback (atomic scatter) if ws can't hold CSR scratch.
// ---------------------------------------------------------------------------
__global__ __launch_bounds__(256) void edge_kernel_atomic(
    const float* __restrict__ vf, const int* __restrict__ ei,
    const float* __restrict__ rad, const float* __restrict__ ev,
    const float* __restrict__ Wr, const float* __restrict__ br,
    const float* __restrict__ fw,
    float* __restrict__ out_s, float* __restrict__ out_v, int E)
{
    const int lane = threadIdx.x & 63;
    const int wid  = __builtin_amdgcn_readfirstlane((int)(threadIdx.x >> 6));
    const int wavesPerBlock = blockDim.x >> 6;
    const int totalWaves = gridDim.x * wavesPerBlock;
    const int w0 = blockIdx.x * wavesPerBlock + wid;

    float c1[RR], c2[RR], c3[RR];
    #pragma unroll
    for (int r = 0; r < RR; ++r) {
        c1[r] = Wr[r * 192 + lane];
        c2[r] = Wr[r * 192 + 64 + lane];
        c3[r] = Wr[r * 192 + 128 + lane];
    }
    const float b1 = br[lane], b2 = br[64 + lane], b3 = br[128 + lane];

    for (int e = w0; e < E; e += totalWaves) {
        const int eu  = __builtin_amdgcn_readfirstlane(e);
        const int src = ei[eu];
        const int tgt = ei[E + eu];

        const float* rp = rad + (size_t)eu * RR;
        float w1 = b1, w2 = b2, w3 = b3;
        #pragma unroll
        for (int r = 0; r < RR; ++r) {
            const float rv = rp[r];
            w1 = fmaf(rv, c1[r], w1);
            w2 = fmaf(rv, c2[r], w2);
            w3 = fmaf(rv, c3[r], w3);
        }

        const float evx = ev[eu * 3 + 0];
        const float evy = ev[eu * 3 + 1];
        const float evz = ev[eu * 3 + 2];

        const float* fp = fw + (size_t)src * 192;
        const float cc1 = fp[lane]       * w1 * INV_SQRT_3;
        const float cc2 = fp[64 + lane]  * w2 * INV_SQRT_3;
        const float cc3 = fp[128 + lane] * w3 * INV_SQRT_3;

        const float* vp = vf + (size_t)src * 192;
        unsafeAtomicAdd(&out_s[(size_t)tgt * 64 + lane], cc3);
        unsafeAtomicAdd(&out_v[(size_t)tgt * 192 + lane],
                        (cc1 * vp[lane] + cc2 * evx) * INV_SQRT_H);
        unsafeAtomicAdd(&out_v[(size_t)tgt * 192 + 64 + lane],
                        (cc1 * vp[64 + lane] + cc2 * evy) * INV_SQRT_H);
        unsafeAtomicAdd(&out_v[(size_t)tgt * 192 + 128 + lane],
                        (cc1 * vp[128 + lane] + cc2 * evz) * INV_SQRT_H);
    }
}

extern "C" void kernel_launch(void* const* d_in, const int* in_sizes, int n_in,
                              void* d_out, int out_size, void* d_ws, size_t ws_size,
                              hipStream_t stream) {
    const float* nf  = (const float*)d_in[0];
    const float* vf  = (const float*)d_in[1];
    const int*   ei  = (const int*)  d_in[2];
    const float* rad = (const float*)d_in[3];
    const float* ev  = (const float*)d_in[4];
    const float* Wf1 = (const float*)d_in[5];
    const float* bf1 = (const float*)d_in[6];
    const float* Wf2 = (const float*)d_in[7];
    const float* bf2 = (const float*)d_in[8];
    const float* Wr  = (const float*)d_in[9];
    const float* br  = (const float*)d_in[10];

    const int N = in_sizes[0] / HH;
    const int E = in_sizes[2] / 2;
    const int nb = (N + SB - 1) / SB;

    float* out_s = (float*)d_out;                // [N,64]
    float* out_v = out_s + (size_t)N * HH;       // [N,3,64]

    // ws layout
    char* ws = (char*)d_ws;
    size_t off = 0;
    float* fw = (float*)(ws + off);  off += (size_t)N * 192 * 4;
    int* cnt  = (int*)(ws + off);    off += (size_t)N * 4;
    int* ptr  = (int*)(ws + off);    off += (size_t)(N + 1) * 4;
    int* head = (int*)(ws + off);    off += (size_t)N * 4;
    int* bsum = (int*)(ws + off);    off += (size_t)nb * 4;
    int* tgtc = (int*)(ws + off);    off += (size_t)E * 4;
    off = (off + 15) & ~(size_t)15;
    int2* pairs = (int2*)(ws + off); off += (size_t)E * 8;

    feat_kernel<<<1024, 192, 0, stream>>>(nf, Wf1, bf1, Wf2, bf2, fw, N);

    // Outputs accumulated via atomic flushes -> zero first.
    hipMemsetAsync(d_out, 0, (size_t)out_size * sizeof(float), stream);

    if (off <= ws_size) {
        // --- CSR build (sort edges by target) ---
        hipMemsetAsync(cnt, 0, (size_t)N * 4, stream);
        hist_kernel<<<2048, 256, 0, stream>>>(ei, cnt, E);
        scanA_kernel<<<nb, SB, 0, stream>>>(cnt, ptr, bsum, N);
        scanB_kernel<<<1, SB, 0, stream>>>(bsum, nb, ptr, N, E);
        scanC_kernel<<<nb, SB, 0, stream>>>(ptr, head, bsum, N);
        fill_kernel<<<2048, 256, 0, stream>>>(ei, head, pairs, tgtc, E);

        // --- fused MFMA projection + segmented aggregation ---
        const int nblk = (E + EPB - 1) / EPB;
        agg_mfma_kernel<<<nblk, 256, 0, stream>>>(vf, rad, ev, Wr, br, fw,
                                                  pairs, tgtc, out_s, out_v, E);
    } else {
        edge_kernel_atomic<<<2048, 256, 0, stream>>>(vf, ei, rad, ev, Wr, br,
                                                     fw, out_s, out_v, E);
    }
}

// Round 4
// 376.522 us; speedup vs baseline: 2.1329x; 1.3231x over previous
//
#include <hip/hip_runtime.h>
#include <hip/hip_bf16.h>

#define HH 64
#define RR 32
#define SILU_SCALE (1.0f / 0.6f)
#define INV_SQRT_3 0.57735026918962576f
#define INV_SQRT_H 0.125f   // 1/sqrt(64)
#define SB 256              // scan block size

typedef __attribute__((ext_vector_type(8))) short short8;
typedef __attribute__((ext_vector_type(4))) float f32x4;

__device__ __forceinline__ int rdlane_i(int v, int l) {
    return __builtin_amdgcn_readlane(v, l);
}
__device__ __forceinline__ float rdlane_f(float v, int l) {
    return __uint_as_float(__builtin_amdgcn_readlane(__float_as_uint(v), l));
}

// ---------------------------------------------------------------------------
// Kernel 1: feat_w = (silu(nf @ Wf1 + bf1) * SILU_SCALE) @ Wf2 + bf2
// 256 threads = 8 sub-groups of 32 lanes; each sub-group owns one node.
// LDS broadcast for node row + hidden vector; padded strides kill bank
// conflicts (8 groups would otherwise alias the same bank).
// ---------------------------------------------------------------------------
__global__ __launch_bounds__(256) void feat2_kernel(
    const float* __restrict__ nf,
    const float* __restrict__ Wf1, const float* __restrict__ bf1,
    const float* __restrict__ Wf2, const float* __restrict__ bf2,
    float* __restrict__ fw, int N)
{
    __shared__ float sW1[64 * 32];
    __shared__ float sW2[32 * 192];
    __shared__ float sb1[32];
    __shared__ float sb2[192];
    __shared__ float snf[8 * 66];   // 64 + 2 pad
    __shared__ float sh[8 * 34];    // 32 + 2 pad

    const int tid = threadIdx.x;
    for (int i = tid; i < 64 * 32; i += 256) sW1[i] = Wf1[i];
    for (int i = tid; i < 32 * 192; i += 256) sW2[i] = Wf2[i];
    if (tid < 32) sb1[tid] = bf1[tid];
    if (tid < 192) sb2[tid] = bf2[tid];
    __syncthreads();

    const int sub = tid >> 5;
    const int l32 = tid & 31;

    for (int n0 = blockIdx.x * 8; n0 < N; n0 += gridDim.x * 8) {
        const int nrem = min(8, N - n0);
        for (int i = tid; i < nrem * 64; i += 256)
            snf[(i >> 6) * 66 + (i & 63)] = nf[(size_t)n0 * 64 + i];
        __syncthreads();

        const int n = n0 + sub;
        {
            float a = sb1[l32];
            const float* x = &snf[sub * 66];
            #pragma unroll
            for (int i = 0; i < 64; ++i)
                a = fmaf(x[i], sW1[i * 32 + l32], a);
            sh[sub * 34 + l32] = a / (1.0f + __expf(-a)) * SILU_SCALE;
        }
        // sh written/read within the same 32-lane group (same wave) -> no barrier
        if (n < N) {
            #pragma unroll
            for (int k = 0; k < 6; ++k) {
                const int col = l32 + 32 * k;
                float o = sb2[col];
                #pragma unroll
                for (int j = 0; j < 32; ++j)
                    o = fmaf(sh[sub * 34 + j], sW2[j * 192 + col], o);
                fw[(size_t)n * 192 + col] = o;
            }
        }
        __syncthreads();   // protect snf before next group load
    }
}

// ---------------------------------------------------------------------------
// Counting sort by target: hist -> scan -> fill (fill also pre-gathers
// rad (as bf16, fragment-ready) and ev into CSR order).
// ---------------------------------------------------------------------------
__global__ __launch_bounds__(256) void hist_kernel(
    const int* __restrict__ ei, int* __restrict__ cnt, int E)
{
    for (int e = blockIdx.x * blockDim.x + threadIdx.x; e < E;
         e += gridDim.x * blockDim.x)
        atomicAdd(&cnt[ei[E + e]], 1);
}

__global__ __launch_bounds__(SB) void scanA_kernel(
    const int* __restrict__ cnt, int* __restrict__ ptr,
    int* __restrict__ bsum, int N)
{
    __shared__ int s[SB];
    const int t = threadIdx.x;
    const int i = blockIdx.x * SB + t;
    const int v = (i < N) ? cnt[i] : 0;
    s[t] = v; __syncthreads();
    for (int off = 1; off < SB; off <<= 1) {
        int x = (t >= off) ? s[t - off] : 0;
        __syncthreads();
        s[t] += x;
        __syncthreads();
    }
    if (i < N) ptr[i] = s[t] - v;
    if (t == SB - 1) bsum[blockIdx.x] = s[t];
}

__global__ __launch_bounds__(SB) void scanB_kernel(
    int* __restrict__ bsum, int nb, int* __restrict__ ptr, int N, int E)
{
    __shared__ int s[SB];
    const int t = threadIdx.x;
    int carry = 0;
    for (int base = 0; base < nb; base += SB) {
        const int i = base + t;
        const int v = (i < nb) ? bsum[i] : 0;
        s[t] = v; __syncthreads();
        for (int off = 1; off < SB; off <<= 1) {
            int x = (t >= off) ? s[t - off] : 0;
            __syncthreads();
            s[t] += x;
            __syncthreads();
        }
        const int total = s[SB - 1];
        if (i < nb) bsum[i] = carry + s[t] - v;
        carry += total;
        __syncthreads();
    }
    if (t == 0) ptr[N] = E;
}

__global__ __launch_bounds__(SB) void scanC_kernel(
    int* __restrict__ ptr, int* __restrict__ head,
    const int* __restrict__ bsum, int N)
{
    const int i = blockIdx.x * SB + threadIdx.x;
    if (i < N) {
        const int p = ptr[i] + bsum[blockIdx.x];
        ptr[i] = p;
        head[i] = p;
    }
}

__global__ __launch_bounds__(256) void fill2_kernel(
    const int* __restrict__ ei,
    const float* __restrict__ rad, const float* __restrict__ ev,
    int* __restrict__ head,
    int* __restrict__ srcS, int* __restrict__ tgtc,
    ushort* __restrict__ radS, float* __restrict__ evS, int E)
{
    for (int e = blockIdx.x * blockDim.x + threadIdx.x; e < E;
         e += gridDim.x * blockDim.x) {
        const int t = ei[E + e];
        const int pos = atomicAdd(&head[t], 1);
        srcS[pos] = ei[e];
        tgtc[pos] = t;
        evS[(size_t)pos * 3 + 0] = ev[(size_t)e * 3 + 0];
        evS[(size_t)pos * 3 + 1] = ev[(size_t)e * 3 + 1];
        evS[(size_t)pos * 3 + 2] = ev[(size_t)e * 3 + 2];
        // rad row -> bf16, sequential read / random 64B write
        const float4* rp = (const float4*)(rad + (size_t)e * RR);
        __align__(16) ushort tmp[32];
        #pragma unroll
        for (int q = 0; q < 8; ++q) {
            float4 rv = rp[q];
            __hip_bfloat16 h0 = __float2bfloat16(rv.x);
            __hip_bfloat16 h1 = __float2bfloat16(rv.y);
            __hip_bfloat16 h2 = __float2bfloat16(rv.z);
            __hip_bfloat16 h3 = __float2bfloat16(rv.w);
            tmp[q * 4 + 0] = *(ushort*)&h0;
            tmp[q * 4 + 1] = *(ushort*)&h1;
            tmp[q * 4 + 2] = *(ushort*)&h2;
            tmp[q * 4 + 3] = *(ushort*)&h3;
        }
        ushort* dst = radS + (size_t)pos * RR;
        #pragma unroll
        for (int q = 0; q < 4; ++q)
            *(short8*)&dst[q * 8] = *(short8*)&tmp[q * 8];
    }
}

// ---------------------------------------------------------------------------
// Wave-independent fused MFMA projection + gather + segmented flush.
// Persistent grid. Each wave grid-strides over 16-edge chunks:
//   - A fragment: one coalesced 16B load from pre-gathered bf16 radS
//   - 12x mfma_f32_16x16x32_bf16 -> P[16][192] bf16 in this wave's private
//     6.4KB LDS slice (swizzled rows, no barriers anywhere)
//   - phase 3: 16 serial edges, 1-deep software pipeline on the 6 fw/vf
//     gather dwords; chunk metadata via readlane (scalar); atomic flush
//     only at target-run boundaries.
// LDS 25.6KB/block; B fragments of Wr live in 48 VGPRs for the whole kernel.
// ---------------------------------------------------------------------------
__global__ __launch_bounds__(256, 4) void agg2_kernel(
    const float*  __restrict__ vf,     // [N,3,64]
    const ushort* __restrict__ radS,   // [E,32] bf16, CSR order
    const float*  __restrict__ evS,    // [E,3]  CSR order
    const float*  __restrict__ Wr,     // [32,192]
    const float*  __restrict__ br,     // [192]
    const float*  __restrict__ fw,     // [N,192]
    const int*    __restrict__ srcS,   // [E] src, CSR order
    const int*    __restrict__ tgtc,   // [E] tgt, CSR order
    float* __restrict__ out_s,         // [N,64]
    float* __restrict__ out_v,         // [N,3,64]
    int E)
{
    __shared__ __align__(16) ushort Pl[4][16 * 200];   // 400B rows, per-wave

    const int tid  = threadIdx.x;
    const int lane = tid & 63;
    const int w    = tid >> 6;
    const int mr   = lane & 15;
    const int kk   = (lane >> 4) * 8;       // k offset in bf16 elems
    const int gwave  = blockIdx.x * 4 + w;
    const int nwaves = gridDim.x * 4;

    // --- B fragments (Wr) in registers: 12 tiles x 4 VGPRs ---
    short8 bfr[12];
    #pragma unroll
    for (int nt = 0; nt < 12; ++nt) {
        short8 b;
        #pragma unroll
        for (int j = 0; j < 8; ++j) {
            __hip_bfloat16 h = __float2bfloat16(Wr[(kk + j) * 192 + nt * 16 + mr]);
            b[j] = *(short*)&h;
        }
        bfr[nt] = b;
    }
    const float b1 = br[lane], b2 = br[64 + lane], b3 = br[128 + lane];
    ushort* Pw = Pl[w];

    const int nchunk = (E + 15) >> 4;
    for (int c = gwave; c < nchunk; c += nwaves) {
        const int base = c << 4;
        const int m = min(16, E - base);
        const int idx = min(base + mr, E - 1);

        const int sv = srcS[idx];
        const int tg = tgtc[idx];
        float evv = 0.f;
        if (lane < 3 * m) evv = evS[(size_t)base * 3 + lane];

        // A fragment: coalesced 16B/lane from pre-gathered bf16 rad
        short8 a0 = *(const short8*)(radS + (size_t)idx * RR + kk);

        // MFMA: P[16][192] = A[16][32] @ Wr[32][192]
        #pragma unroll
        for (int nt = 0; nt < 12; ++nt) {
            f32x4 c0 = {0.f, 0.f, 0.f, 0.f};
            c0 = __builtin_amdgcn_mfma_f32_16x16x32_bf16(a0, bfr[nt], c0, 0, 0, 0);
            #pragma unroll
            for (int r = 0; r < 4; ++r) {
                const int row = ((lane >> 4) << 2) + r;   // C: row=(lane>>4)*4+reg
                __hip_bfloat16 h = __float2bfloat16(c0[r]);
                *(ushort*)((char*)Pw + row * 400 +
                           ((nt * 32 + mr * 2) ^ ((row & 12) << 3))) = *(ushort*)&h;
            }
        }

        // run-boundary flags (per CSR slot, held in lanes 0..15)
        const int tnext = __shfl(tg, min(mr + 1, 15));
        const int bnd = (mr == m - 1) || (tnext != tg);

        // --- phase 3: serial sweep, 1-deep pipelined gathers ---
        float as = 0.f, ax = 0.f, ay = 0.f, az = 0.f;
        {
            const int s0 = rdlane_i(sv, 0);
            const float* fp = fw + (size_t)s0 * 192;
            const float* vp = vf + (size_t)s0 * 192;
            float f1 = fp[lane], f2 = fp[64 + lane], f3 = fp[128 + lane];
            float v1 = vp[lane], v2 = vp[64 + lane], v3 = vp[128 + lane];

            for (int i = 0; i < m; ++i) {
                // issue next edge's gathers (clamped; redundant on last iter)
                const int inext = min(i + 1, m - 1);
                const int sn = rdlane_i(sv, inext);
                const float* fpn = fw + (size_t)sn * 192;
                const float* vpn = vf + (size_t)sn * 192;
                const float nf1 = fpn[lane], nf2 = fpn[64 + lane], nf3 = fpn[128 + lane];
                const float nv1 = vpn[lane], nv2 = vpn[64 + lane], nv3 = vpn[128 + lane];

                const int t  = rdlane_i(tg, i);
                const int fl = rdlane_i(bnd, i);
                const float ex = rdlane_f(evv, 3 * i + 0);
                const float ey = rdlane_f(evv, 3 * i + 1);
                const float ez = rdlane_f(evv, 3 * i + 2);

                const int swz = (i & 12) << 3;
                const char* prow = (const char*)Pw + i * 400;
                ushort u1 = *(const ushort*)(prow + ((lane * 2) ^ swz));
                ushort u2 = *(const ushort*)(prow + (((64 + lane) * 2) ^ swz));
                ushort u3 = *(const ushort*)(prow + (((128 + lane) * 2) ^ swz));
                const float p1 = __bfloat162float(*(__hip_bfloat16*)&u1) + b1;
                const float p2 = __bfloat162float(*(__hip_bfloat16*)&u2) + b2;
                const float p3 = __bfloat162float(*(__hip_bfloat16*)&u3) + b3;

                const float cc1 = f1 * p1 * INV_SQRT_3;
                const float cc2 = f2 * p2 * INV_SQRT_3;
                const float cc3 = f3 * p3 * INV_SQRT_3;

                as += cc3;
                ax = fmaf(cc1, v1, fmaf(cc2, ex, ax));
                ay = fmaf(cc1, v2, fmaf(cc2, ey, ay));
                az = fmaf(cc1, v3, fmaf(cc2, ez, az));

                if (fl) {   // wave-uniform (scalar) branch
                    unsafeAtomicAdd(&out_s[(size_t)t * 64 + lane], as);
                    unsafeAtomicAdd(&out_v[(size_t)t * 192 + lane],       ax * INV_SQRT_H);
                    unsafeAtomicAdd(&out_v[(size_t)t * 192 + 64 + lane],  ay * INV_SQRT_H);
                    unsafeAtomicAdd(&out_v[(size_t)t * 192 + 128 + lane], az * INV_SQRT_H);
                    as = ax = ay = az = 0.f;
                }
                f1 = nf1; f2 = nf2; f3 = nf3;
                v1 = nv1; v2 = nv2; v3 = nv3;
            }
        }
    }
}

// ---------------------------------------------------------------------------
// Fallback (atomic scatter) if ws can't hold scratch.
// ---------------------------------------------------------------------------
__global__ __launch_bounds__(256) void edge_kernel_atomic(
    const float* __restrict__ vf, const int* __restrict__ ei,
    const float* __restrict__ rad, const float* __restrict__ ev,
    const float* __restrict__ Wr, const float* __restrict__ br,
    const float* __restrict__ fw,
    float* __restrict__ out_s, float* __restrict__ out_v, int E)
{
    const int lane = threadIdx.x & 63;
    const int wid  = __builtin_amdgcn_readfirstlane((int)(threadIdx.x >> 6));
    const int wavesPerBlock = blockDim.x >> 6;
    const int totalWaves = gridDim.x * wavesPerBlock;
    const int w0 = blockIdx.x * wavesPerBlock + wid;

    float c1[RR], c2[RR], c3[RR];
    #pragma unroll
    for (int r = 0; r < RR; ++r) {
        c1[r] = Wr[r * 192 + lane];
        c2[r] = Wr[r * 192 + 64 + lane];
        c3[r] = Wr[r * 192 + 128 + lane];
    }
    const float b1 = br[lane], b2 = br[64 + lane], b3 = br[128 + lane];

    for (int e = w0; e < E; e += totalWaves) {
        const int eu  = __builtin_amdgcn_readfirstlane(e);
        const int src = ei[eu];
        const int tgt = ei[E + eu];

        const float* rp = rad + (size_t)eu * RR;
        float w1 = b1, w2 = b2, w3 = b3;
        #pragma unroll
        for (int r = 0; r < RR; ++r) {
            const float rv = rp[r];
            w1 = fmaf(rv, c1[r], w1);
            w2 = fmaf(rv, c2[r], w2);
            w3 = fmaf(rv, c3[r], w3);
        }

        const float evx = ev[eu * 3 + 0];
        const float evy = ev[eu * 3 + 1];
        const float evz = ev[eu * 3 + 2];

        const float* fp = fw + (size_t)src * 192;
        const float cc1 = fp[lane]       * w1 * INV_SQRT_3;
        const float cc2 = fp[64 + lane]  * w2 * INV_SQRT_3;
        const float cc3 = fp[128 + lane] * w3 * INV_SQRT_3;

        const float* vp = vf + (size_t)src * 192;
        unsafeAtomicAdd(&out_s[(size_t)tgt * 64 + lane], cc3);
        unsafeAtomicAdd(&out_v[(size_t)tgt * 192 + lane],
                        (cc1 * vp[lane] + cc2 * evx) * INV_SQRT_H);
        unsafeAtomicAdd(&out_v[(size_t)tgt * 192 + 64 + lane],
                        (cc1 * vp[64 + lane] + cc2 * evy) * INV_SQRT_H);
        unsafeAtomicAdd(&out_v[(size_t)tgt * 192 + 128 + lane],
                        (cc1 * vp[128 + lane] + cc2 * evz) * INV_SQRT_H);
    }
}

extern "C" void kernel_launch(void* const* d_in, const int* in_sizes, int n_in,
                              void* d_out, int out_size, void* d_ws, size_t ws_size,
                              hipStream_t stream) {
    const float* nf  = (const float*)d_in[0];
    const float* vf  = (const float*)d_in[1];
    const int*   ei  = (const int*)  d_in[2];
    const float* rad = (const float*)d_in[3];
    const float* ev  = (const float*)d_in[4];
    const float* Wf1 = (const float*)d_in[5];
    const float* bf1 = (const float*)d_in[6];
    const float* Wf2 = (const float*)d_in[7];
    const float* bf2 = (const float*)d_in[8];
    const float* Wr  = (const float*)d_in[9];
    const float* br  = (const float*)d_in[10];

    const int N = in_sizes[0] / HH;
    const int E = in_sizes[2] / 2;
    const int nb = (N + SB - 1) / SB;

    float* out_s = (float*)d_out;                // [N,64]
    float* out_v = out_s + (size_t)N * HH;       // [N,3,64]

    // ws layout
    char* ws = (char*)d_ws;
    size_t off = 0;
    float* fw = (float*)(ws + off);   off += (size_t)N * 192 * 4;
    int* cnt  = (int*)(ws + off);     off += (size_t)N * 4;
    int* ptr  = (int*)(ws + off);     off += (size_t)(N + 1) * 4;
    int* head = (int*)(ws + off);     off += (size_t)N * 4;
    int* bsum = (int*)(ws + off);     off += (size_t)nb * 4;
    int* srcS = (int*)(ws + off);     off += (size_t)E * 4;
    int* tgtc = (int*)(ws + off);     off += (size_t)E * 4;
    off = (off + 15) & ~(size_t)15;
    float* evS = (float*)(ws + off);  off += (size_t)E * 3 * 4;
    off = (off + 15) & ~(size_t)15;
    ushort* radS = (ushort*)(ws + off); off += (size_t)E * RR * 2;

    const int fgrid = min(1280, (N + 7) / 8) > 0 ? min(1280, (N + 7) / 8) : 1;
    feat2_kernel<<<fgrid, 256, 0, stream>>>(nf, Wf1, bf1, Wf2, bf2, fw, N);

    // outputs accumulated via atomic flushes -> zero first
    hipMemsetAsync(d_out, 0, (size_t)out_size * sizeof(float), stream);

    if (off <= ws_size) {
        hipMemsetAsync(cnt, 0, (size_t)N * 4, stream);
        hist_kernel<<<2048, 256, 0, stream>>>(ei, cnt, E);
        scanA_kernel<<<nb, SB, 0, stream>>>(cnt, ptr, bsum, N);
        scanB_kernel<<<1, SB, 0, stream>>>(bsum, nb, ptr, N, E);
        scanC_kernel<<<nb, SB, 0, stream>>>(ptr, head, bsum, N);
        fill2_kernel<<<2048, 256, 0, stream>>>(ei, rad, ev, head,
                                               srcS, tgtc, radS, evS, E);

        agg2_kernel<<<1024, 256, 0, stream>>>(vf, radS, evS, Wr, br, fw,
                                              srcS, tgtc, out_s, out_v, E);
    } else {
        edge_kernel_atomic<<<2048, 256, 0, stream>>>(vf, ei, rad, ev, Wr, br,
                                                     fw, out_s, out_v, E);
    }
}

// Round 5
// 363.279 us; speedup vs baseline: 2.2106x; 1.0365x over previous
//
#include <hip/hip_runtime.h>
#include <hip/hip_bf16.h>

#define HH 64
#define RR 32
#define SILU_SCALE (1.0f / 0.6f)
#define INV_SQRT_3 0.57735026918962576f
#define INV_SQRT_H 0.125f   // 1/sqrt(64)
#define SB 256              // scan block size

typedef __attribute__((ext_vector_type(8))) short short8;
typedef __attribute__((ext_vector_type(4))) float f32x4;

__device__ __forceinline__ int rdlane_i(int v, int l) {
    return __builtin_amdgcn_readlane(v, l);
}
__device__ __forceinline__ float rdlane_f(float v, int l) {
    return __uint_as_float(__builtin_amdgcn_readlane(__float_as_uint(v), l));
}
__device__ __forceinline__ ushort bf16u(float x) {
    __hip_bfloat16 h = __float2bfloat16(x);
    return *(ushort*)&h;
}

// ---------------------------------------------------------------------------
// Kernel 1: compute feat_w and write PACKED table
//   pk[n][col] = (bf16(feat_w[n][col]) << 16) | bf16(vf[n][col])
// 256 threads = 8 sub-groups of 32 lanes; each sub-group owns one node.
// ---------------------------------------------------------------------------
__global__ __launch_bounds__(256) void feat2_kernel(
    const float* __restrict__ nf,
    const float* __restrict__ vf,
    const float* __restrict__ Wf1, const float* __restrict__ bf1,
    const float* __restrict__ Wf2, const float* __restrict__ bf2,
    unsigned int* __restrict__ pk, int N)
{
    __shared__ float sW1[64 * 32];
    __shared__ float sW2[32 * 192];
    __shared__ float sb1[32];
    __shared__ float sb2[192];
    __shared__ float snf[8 * 66];   // 64 + 2 pad
    __shared__ float sh[8 * 34];    // 32 + 2 pad

    const int tid = threadIdx.x;
    for (int i = tid; i < 64 * 32; i += 256) sW1[i] = Wf1[i];
    for (int i = tid; i < 32 * 192; i += 256) sW2[i] = Wf2[i];
    if (tid < 32) sb1[tid] = bf1[tid];
    if (tid < 192) sb2[tid] = bf2[tid];
    __syncthreads();

    const int sub = tid >> 5;
    const int l32 = tid & 31;

    for (int n0 = blockIdx.x * 8; n0 < N; n0 += gridDim.x * 8) {
        const int nrem = min(8, N - n0);
        for (int i = tid; i < nrem * 64; i += 256)
            snf[(i >> 6) * 66 + (i & 63)] = nf[(size_t)n0 * 64 + i];
        __syncthreads();

        const int n = n0 + sub;
        {
            float a = sb1[l32];
            const float* x = &snf[sub * 66];
            #pragma unroll
            for (int i = 0; i < 64; ++i)
                a = fmaf(x[i], sW1[i * 32 + l32], a);
            sh[sub * 34 + l32] = a / (1.0f + __expf(-a)) * SILU_SCALE;
        }
        // sh written/read within the same 32-lane group -> no barrier
        if (n < N) {
            #pragma unroll
            for (int k = 0; k < 6; ++k) {
                const int col = l32 + 32 * k;
                const float vvf = vf[(size_t)n * 192 + col];
                float o = sb2[col];
                #pragma unroll
                for (int j = 0; j < 32; ++j)
                    o = fmaf(sh[sub * 34 + j], sW2[j * 192 + col], o);
                pk[(size_t)n * 192 + col] =
                    ((unsigned int)bf16u(o) << 16) | (unsigned int)bf16u(vvf);
            }
        }
        __syncthreads();
    }
}

// ---------------------------------------------------------------------------
// Counting sort by target: hist -> scan -> fill (fill pre-gathers rad->bf16
// and ev into CSR order).
// ---------------------------------------------------------------------------
__global__ __launch_bounds__(256) void hist_kernel(
    const int* __restrict__ ei, int* __restrict__ cnt, int E)
{
    for (int e = blockIdx.x * blockDim.x + threadIdx.x; e < E;
         e += gridDim.x * blockDim.x)
        atomicAdd(&cnt[ei[E + e]], 1);
}

__global__ __launch_bounds__(SB) void scanA_kernel(
    const int* __restrict__ cnt, int* __restrict__ ptr,
    int* __restrict__ bsum, int N)
{
    __shared__ int s[SB];
    const int t = threadIdx.x;
    const int i = blockIdx.x * SB + t;
    const int v = (i < N) ? cnt[i] : 0;
    s[t] = v; __syncthreads();
    for (int off = 1; off < SB; off <<= 1) {
        int x = (t >= off) ? s[t - off] : 0;
        __syncthreads();
        s[t] += x;
        __syncthreads();
    }
    if (i < N) ptr[i] = s[t] - v;
    if (t == SB - 1) bsum[blockIdx.x] = s[t];
}

__global__ __launch_bounds__(SB) void scanB_kernel(
    int* __restrict__ bsum, int nb, int* __restrict__ ptr, int N, int E)
{
    __shared__ int s[SB];
    const int t = threadIdx.x;
    int carry = 0;
    for (int base = 0; base < nb; base += SB) {
        const int i = base + t;
        const int v = (i < nb) ? bsum[i] : 0;
        s[t] = v; __syncthreads();
        for (int off = 1; off < SB; off <<= 1) {
            int x = (t >= off) ? s[t - off] : 0;
            __syncthreads();
            s[t] += x;
            __syncthreads();
        }
        const int total = s[SB - 1];
        if (i < nb) bsum[i] = carry + s[t] - v;
        carry += total;
        __syncthreads();
    }
    if (t == 0) ptr[N] = E;
}

__global__ __launch_bounds__(SB) void scanC_kernel(
    int* __restrict__ ptr, int* __restrict__ head,
    const int* __restrict__ bsum, int N)
{
    const int i = blockIdx.x * SB + threadIdx.x;
    if (i < N) {
        const int p = ptr[i] + bsum[blockIdx.x];
        ptr[i] = p;
        head[i] = p;
    }
}

__global__ __launch_bounds__(256) void fill2_kernel(
    const int* __restrict__ ei,
    const float* __restrict__ rad, const float* __restrict__ ev,
    int* __restrict__ head,
    int* __restrict__ srcS, int* __restrict__ tgtc,
    ushort* __restrict__ radS, float* __restrict__ evS, int E)
{
    for (int e = blockIdx.x * blockDim.x + threadIdx.x; e < E;
         e += gridDim.x * blockDim.x) {
        const int t = ei[E + e];
        const int pos = atomicAdd(&head[t], 1);
        srcS[pos] = ei[e];
        tgtc[pos] = t;
        evS[(size_t)pos * 3 + 0] = ev[(size_t)e * 3 + 0];
        evS[(size_t)pos * 3 + 1] = ev[(size_t)e * 3 + 1];
        evS[(size_t)pos * 3 + 2] = ev[(size_t)e * 3 + 2];
        const float4* rp = (const float4*)(rad + (size_t)e * RR);
        __align__(16) ushort tmp[32];
        #pragma unroll
        for (int q = 0; q < 8; ++q) {
            float4 rv = rp[q];
            tmp[q * 4 + 0] = bf16u(rv.x);
            tmp[q * 4 + 1] = bf16u(rv.y);
            tmp[q * 4 + 2] = bf16u(rv.z);
            tmp[q * 4 + 3] = bf16u(rv.w);
        }
        ushort* dst = radS + (size_t)pos * RR;
        #pragma unroll
        for (int q = 0; q < 4; ++q)
            *(short8*)&dst[q * 8] = *(short8*)&tmp[q * 8];
    }
}

// ---------------------------------------------------------------------------
// Wave-independent fused MFMA projection + packed gather + segmented flush.
// Grid 1536 = 6 blocks/CU (LDS-capped); launch_bounds(256,6) pins VGPR<=85.
// ---------------------------------------------------------------------------
__global__ __launch_bounds__(256, 6) void agg2_kernel(
    const unsigned int* __restrict__ pk,   // [N,192] packed bf16 (fw|vf)
    const ushort* __restrict__ radS,       // [E,32] bf16, CSR order
    const float*  __restrict__ evS,        // [E,3]  CSR order
    const float*  __restrict__ Wr,         // [32,192]
    const float*  __restrict__ br,         // [192]
    const int*    __restrict__ srcS,       // [E] src, CSR order
    const int*    __restrict__ tgtc,       // [E] tgt, CSR order
    float* __restrict__ out_s,             // [N,64]
    float* __restrict__ out_v,             // [N,3,64]
    int E)
{
    __shared__ __align__(16) ushort Pl[4][16 * 200];   // 400B rows, per-wave

    const int tid  = threadIdx.x;
    const int lane = tid & 63;
    const int w    = tid >> 6;
    const int mr   = lane & 15;
    const int kk   = (lane >> 4) * 8;       // k offset in bf16 elems
    const int gwave  = blockIdx.x * 4 + w;
    const int nwaves = gridDim.x * 4;

    // B fragments (Wr) in registers: 12 tiles x 4 VGPRs = 48 VGPRs
    short8 bfr[12];
    #pragma unroll
    for (int nt = 0; nt < 12; ++nt) {
        short8 b;
        #pragma unroll
        for (int j = 0; j < 8; ++j)
            b[j] = (short)bf16u(Wr[(kk + j) * 192 + nt * 16 + mr]);
        bfr[nt] = b;
    }
    const float b1 = br[lane], b2 = br[64 + lane], b3 = br[128 + lane];
    ushort* Pw = Pl[w];

    const int nchunk = (E + 15) >> 4;
    for (int c = gwave; c < nchunk; c += nwaves) {
        const int base = c << 4;
        const int m = min(16, E - base);
        const int idx = min(base + mr, E - 1);

        const int sv = srcS[idx];
        const int tg = tgtc[idx];
        float evv = 0.f;
        if (lane < 3 * m) evv = evS[(size_t)base * 3 + lane];

        // A fragment: coalesced 16B/lane from pre-gathered bf16 rad
        short8 a0 = *(const short8*)(radS + (size_t)idx * RR + kk);

        // MFMA: P[16][192] = A[16][32] @ Wr[32][192] -> bf16 LDS (swizzled)
        #pragma unroll
        for (int nt = 0; nt < 12; ++nt) {
            f32x4 c0 = {0.f, 0.f, 0.f, 0.f};
            c0 = __builtin_amdgcn_mfma_f32_16x16x32_bf16(a0, bfr[nt], c0, 0, 0, 0);
            #pragma unroll
            for (int r = 0; r < 4; ++r) {
                const int row = ((lane >> 4) << 2) + r;   // C: row=(lane>>4)*4+reg
                *(ushort*)((char*)Pw + row * 400 +
                           ((nt * 32 + mr * 2) ^ ((row & 12) << 3))) = bf16u(c0[r]);
            }
        }

        // run-boundary flags (per CSR slot, lanes 0..15, replicated)
        const int tnext = __shfl(tg, min(mr + 1, 15));
        const int bnd = (mr == m - 1) || (tnext != tg);

        // --- phase 3: serial sweep, 1-deep pipelined packed gathers ---
        float as = 0.f, ax = 0.f, ay = 0.f, az = 0.f;
        {
            const int s0 = rdlane_i(sv, 0);
            const unsigned int* pp = pk + (size_t)s0 * 192;
            unsigned int u1 = pp[lane], u2 = pp[64 + lane], u3 = pp[128 + lane];

            for (int i = 0; i < m; ++i) {
                // issue next edge's gathers (clamped; redundant on last iter)
                const int inext = min(i + 1, m - 1);
                const int sn = rdlane_i(sv, inext);
                const unsigned int* ppn = pk + (size_t)sn * 192;
                const unsigned int n1 = ppn[lane];
                const unsigned int n2 = ppn[64 + lane];
                const unsigned int n3 = ppn[128 + lane];

                const int t  = rdlane_i(tg, i);
                const int fl = rdlane_i(bnd, i);
                const float ex = rdlane_f(evv, 3 * i + 0);
                const float ey = rdlane_f(evv, 3 * i + 1);
                const float ez = rdlane_f(evv, 3 * i + 2);

                const int swz = (i & 12) << 3;
                const char* prow = (const char*)Pw + i * 400;
                ushort q1 = *(const ushort*)(prow + ((lane * 2) ^ swz));
                ushort q2 = *(const ushort*)(prow + (((64 + lane) * 2) ^ swz));
                ushort q3 = *(const ushort*)(prow + (((128 + lane) * 2) ^ swz));
                const float p1 = __uint_as_float((unsigned int)q1 << 16) + b1;
                const float p2 = __uint_as_float((unsigned int)q2 << 16) + b2;
                const float p3 = __uint_as_float((unsigned int)q3 << 16) + b3;

                const float f1 = __uint_as_float(u1 & 0xFFFF0000u);
                const float f2 = __uint_as_float(u2 & 0xFFFF0000u);
                const float f3 = __uint_as_float(u3 & 0xFFFF0000u);
                const float v1 = __uint_as_float(u1 << 16);
                const float v2 = __uint_as_float(u2 << 16);
                const float v3 = __uint_as_float(u3 << 16);

                const float cc1 = f1 * p1 * INV_SQRT_3;
                const float cc2 = f2 * p2 * INV_SQRT_3;
                const float cc3 = f3 * p3 * INV_SQRT_3;

                as += cc3;
                ax = fmaf(cc1, v1, fmaf(cc2, ex, ax));
                ay = fmaf(cc1, v2, fmaf(cc2, ey, ay));
                az = fmaf(cc1, v3, fmaf(cc2, ez, az));

                if (fl) {   // wave-uniform (scalar) branch
                    unsafeAtomicAdd(&out_s[(size_t)t * 64 + lane], as);
                    unsafeAtomicAdd(&out_v[(size_t)t * 192 + lane],       ax * INV_SQRT_H);
                    unsafeAtomicAdd(&out_v[(size_t)t * 192 + 64 + lane],  ay * INV_SQRT_H);
                    unsafeAtomicAdd(&out_v[(size_t)t * 192 + 128 + lane], az * INV_SQRT_H);
                    as = ax = ay = az = 0.f;
                }
                u1 = n1; u2 = n2; u3 = n3;
            }
        }
    }
}

// ---------------------------------------------------------------------------
// Fallback (atomic scatter) if ws can't hold scratch; uses packed table.
// ---------------------------------------------------------------------------
__global__ __launch_bounds__(256) void edge_kernel_atomic(
    const unsigned int* __restrict__ pk, const int* __restrict__ ei,
    const float* __restrict__ rad, const float* __restrict__ ev,
    const float* __restrict__ Wr, const float* __restrict__ br,
    float* __restrict__ out_s, float* __restrict__ out_v, int E)
{
    const int lane = threadIdx.x & 63;
    const int wid  = __builtin_amdgcn_readfirstlane((int)(threadIdx.x >> 6));
    const int wavesPerBlock = blockDim.x >> 6;
    const int totalWaves = gridDim.x * wavesPerBlock;
    const int w0 = blockIdx.x * wavesPerBlock + wid;

    float c1[RR], c2[RR], c3[RR];
    #pragma unroll
    for (int r = 0; r < RR; ++r) {
        c1[r] = Wr[r * 192 + lane];
        c2[r] = Wr[r * 192 + 64 + lane];
        c3[r] = Wr[r * 192 + 128 + lane];
    }
    const float b1 = br[lane], b2 = br[64 + lane], b3 = br[128 + lane];

    for (int e = w0; e < E; e += totalWaves) {
        const int eu  = __builtin_amdgcn_readfirstlane(e);
        const int src = ei[eu];
        const int tgt = ei[E + eu];

        const float* rp = rad + (size_t)eu * RR;
        float w1 = b1, w2 = b2, w3 = b3;
        #pragma unroll
        for (int r = 0; r < RR; ++r) {
            const float rv = rp[r];
            w1 = fmaf(rv, c1[r], w1);
            w2 = fmaf(rv, c2[r], w2);
            w3 = fmaf(rv, c3[r], w3);
        }

        const float evx = ev[eu * 3 + 0];
        const float evy = ev[eu * 3 + 1];
        const float evz = ev[eu * 3 + 2];

        const unsigned int* pp = pk + (size_t)src * 192;
        const unsigned int u1 = pp[lane], u2 = pp[64 + lane], u3 = pp[128 + lane];
        const float f1 = __uint_as_float(u1 & 0xFFFF0000u);
        const float f2 = __uint_as_float(u2 & 0xFFFF0000u);
        const float f3 = __uint_as_float(u3 & 0xFFFF0000u);
        const float v1 = __uint_as_float(u1 << 16);
        const float v2 = __uint_as_float(u2 << 16);
        const float v3 = __uint_as_float(u3 << 16);

        const float cc1 = f1 * w1 * INV_SQRT_3;
        const float cc2 = f2 * w2 * INV_SQRT_3;
        const float cc3 = f3 * w3 * INV_SQRT_3;

        unsafeAtomicAdd(&out_s[(size_t)tgt * 64 + lane], cc3);
        unsafeAtomicAdd(&out_v[(size_t)tgt * 192 + lane],
                        (cc1 * v1 + cc2 * evx) * INV_SQRT_H);
        unsafeAtomicAdd(&out_v[(size_t)tgt * 192 + 64 + lane],
                        (cc1 * v2 + cc2 * evy) * INV_SQRT_H);
        unsafeAtomicAdd(&out_v[(size_t)tgt * 192 + 128 + lane],
                        (cc1 * v3 + cc2 * evz) * INV_SQRT_H);
    }
}

extern "C" void kernel_launch(void* const* d_in, const int* in_sizes, int n_in,
                              void* d_out, int out_size, void* d_ws, size_t ws_size,
                              hipStream_t stream) {
    const float* nf  = (const float*)d_in[0];
    const float* vf  = (const float*)d_in[1];
    const int*   ei  = (const int*)  d_in[2];
    const float* rad = (const float*)d_in[3];
    const float* ev  = (const float*)d_in[4];
    const float* Wf1 = (const float*)d_in[5];
    const float* bf1 = (const float*)d_in[6];
    const float* Wf2 = (const float*)d_in[7];
    const float* bf2 = (const float*)d_in[8];
    const float* Wr  = (const float*)d_in[9];
    const float* br  = (const float*)d_in[10];

    const int N = in_sizes[0] / HH;
    const int E = in_sizes[2] / 2;
    const int nb = (N + SB - 1) / SB;

    float* out_s = (float*)d_out;                // [N,64]
    float* out_v = out_s + (size_t)N * HH;       // [N,3,64]

    // ws layout
    char* ws = (char*)d_ws;
    size_t off = 0;
    unsigned int* pkt = (unsigned int*)(ws + off); off += (size_t)N * 192 * 4;
    int* cnt  = (int*)(ws + off);     off += (size_t)N * 4;
    int* ptr  = (int*)(ws + off);     off += (size_t)(N + 1) * 4;
    int* head = (int*)(ws + off);     off += (size_t)N * 4;
    int* bsum = (int*)(ws + off);     off += (size_t)nb * 4;
    int* srcS = (int*)(ws + off);     off += (size_t)E * 4;
    int* tgtc = (int*)(ws + off);     off += (size_t)E * 4;
    off = (off + 15) & ~(size_t)15;
    float* evS = (float*)(ws + off);  off += (size_t)E * 3 * 4;
    off = (off + 15) & ~(size_t)15;
    ushort* radS = (ushort*)(ws + off); off += (size_t)E * RR * 2;

    const int fgrid = min(1280, (N + 7) / 8) > 0 ? min(1280, (N + 7) / 8) : 1;
    feat2_kernel<<<fgrid, 256, 0, stream>>>(nf, vf, Wf1, bf1, Wf2, bf2, pkt, N);

    // outputs accumulated via atomic flushes -> zero first
    hipMemsetAsync(d_out, 0, (size_t)out_size * sizeof(float), stream);

    if (off <= ws_size) {
        hipMemsetAsync(cnt, 0, (size_t)N * 4, stream);
        hist_kernel<<<2048, 256, 0, stream>>>(ei, cnt, E);
        scanA_kernel<<<nb, SB, 0, stream>>>(cnt, ptr, bsum, N);
        scanB_kernel<<<1, SB, 0, stream>>>(bsum, nb, ptr, N, E);
        scanC_kernel<<<nb, SB, 0, stream>>>(ptr, head, bsum, N);
        fill2_kernel<<<2048, 256, 0, stream>>>(ei, rad, ev, head,
                                               srcS, tgtc, radS, evS, E);

        const int nchunk = (E + 15) >> 4;
        const int agrid = min(1536, (nchunk + 3) / 4);
        agg2_kernel<<<agrid, 256, 0, stream>>>(pkt, radS, evS, Wr, br,
                                               srcS, tgtc, out_s, out_v, E);
    } else {
        edge_kernel_atomic<<<2048, 256, 0, stream>>>(pkt, ei, rad, ev, Wr, br,
                                                     out_s, out_v, E);
    }
}

// Round 6
// 355.914 us; speedup vs baseline: 2.2564x; 1.0207x over previous
//
#include <hip/hip_runtime.h>
#include <hip/hip_bf16.h>

#define HH 64
#define RR 32
#define SILU_SCALE (1.0f / 0.6f)
#define INV_SQRT_3 0.57735026918962576f
#define INV_SQRT_H 0.125f   // 1/sqrt(64)
#define SB 256              // scan block size

typedef __attribute__((ext_vector_type(8))) short short8;
typedef __attribute__((ext_vector_type(4))) float f32x4;

__device__ __forceinline__ int rdlane_i(int v, int l) {
    return __builtin_amdgcn_readlane(v, l);
}
__device__ __forceinline__ ushort bf16u(float x) {
    __hip_bfloat16 h = __float2bfloat16(x);
    return *(ushort*)&h;
}

// ---------------------------------------------------------------------------
// Kernel 1: compute feat_w and write PACKED table
//   pk[n][col] = (bf16(feat_w[n][col]) << 16) | bf16(vf[n][col])
// ---------------------------------------------------------------------------
__global__ __launch_bounds__(256) void feat2_kernel(
    const float* __restrict__ nf,
    const float* __restrict__ vf,
    const float* __restrict__ Wf1, const float* __restrict__ bf1,
    const float* __restrict__ Wf2, const float* __restrict__ bf2,
    unsigned int* __restrict__ pk, int N)
{
    __shared__ float sW1[64 * 32];
    __shared__ float sW2[32 * 192];
    __shared__ float sb1[32];
    __shared__ float sb2[192];
    __shared__ float snf[8 * 66];   // 64 + 2 pad
    __shared__ float sh[8 * 34];    // 32 + 2 pad

    const int tid = threadIdx.x;
    for (int i = tid; i < 64 * 32; i += 256) sW1[i] = Wf1[i];
    for (int i = tid; i < 32 * 192; i += 256) sW2[i] = Wf2[i];
    if (tid < 32) sb1[tid] = bf1[tid];
    if (tid < 192) sb2[tid] = bf2[tid];
    __syncthreads();

    const int sub = tid >> 5;
    const int l32 = tid & 31;

    for (int n0 = blockIdx.x * 8; n0 < N; n0 += gridDim.x * 8) {
        const int nrem = min(8, N - n0);
        for (int i = tid; i < nrem * 64; i += 256)
            snf[(i >> 6) * 66 + (i & 63)] = nf[(size_t)n0 * 64 + i];
        __syncthreads();

        const int n = n0 + sub;
        {
            float a = sb1[l32];
            const float* x = &snf[sub * 66];
            #pragma unroll
            for (int i = 0; i < 64; ++i)
                a = fmaf(x[i], sW1[i * 32 + l32], a);
            sh[sub * 34 + l32] = a / (1.0f + __expf(-a)) * SILU_SCALE;
        }
        // sh written/read within the same 32-lane group -> no barrier
        if (n < N) {
            #pragma unroll
            for (int k = 0; k < 6; ++k) {
                const int col = l32 + 32 * k;
                const float vvf = vf[(size_t)n * 192 + col];
                float o = sb2[col];
                #pragma unroll
                for (int j = 0; j < 32; ++j)
                    o = fmaf(sh[sub * 34 + j], sW2[j * 192 + col], o);
                pk[(size_t)n * 192 + col] =
                    ((unsigned int)bf16u(o) << 16) | (unsigned int)bf16u(vvf);
            }
        }
        __syncthreads();
    }
}

// ---------------------------------------------------------------------------
// hist (atomic count per target) fused with rad -> bf16 edge-order convert
// (sequential read, sequential write — no random scatter here).
// ---------------------------------------------------------------------------
__global__ __launch_bounds__(256) void histconv_kernel(
    const int* __restrict__ ei, const float* __restrict__ rad,
    int* __restrict__ cnt, ushort* __restrict__ radB, int E)
{
    for (int e = blockIdx.x * blockDim.x + threadIdx.x; e < E;
         e += gridDim.x * blockDim.x) {
        atomicAdd(&cnt[ei[E + e]], 1);
        const float4* rp = (const float4*)(rad + (size_t)e * RR);
        __align__(16) ushort tmp[32];
        #pragma unroll
        for (int q = 0; q < 8; ++q) {
            float4 rv = rp[q];
            tmp[q * 4 + 0] = bf16u(rv.x);
            tmp[q * 4 + 1] = bf16u(rv.y);
            tmp[q * 4 + 2] = bf16u(rv.z);
            tmp[q * 4 + 3] = bf16u(rv.w);
        }
        ushort* dst = radB + (size_t)e * RR;
        #pragma unroll
        for (int q = 0; q < 4; ++q)
            *(short8*)&dst[q * 8] = *(short8*)&tmp[q * 8];
    }
}

__global__ __launch_bounds__(SB) void scanA_kernel(
    const int* __restrict__ cnt, int* __restrict__ ptr,
    int* __restrict__ bsum, int N)
{
    __shared__ int s[SB];
    const int t = threadIdx.x;
    const int i = blockIdx.x * SB + t;
    const int v = (i < N) ? cnt[i] : 0;
    s[t] = v; __syncthreads();
    for (int off = 1; off < SB; off <<= 1) {
        int x = (t >= off) ? s[t - off] : 0;
        __syncthreads();
        s[t] += x;
        __syncthreads();
    }
    if (i < N) ptr[i] = s[t] - v;
    if (t == SB - 1) bsum[blockIdx.x] = s[t];
}

__global__ __launch_bounds__(SB) void scanB_kernel(
    int* __restrict__ bsum, int nb, int* __restrict__ ptr, int N, int E)
{
    __shared__ int s[SB];
    const int t = threadIdx.x;
    int carry = 0;
    for (int base = 0; base < nb; base += SB) {
        const int i = base + t;
        const int v = (i < nb) ? bsum[i] : 0;
        s[t] = v; __syncthreads();
        for (int off = 1; off < SB; off <<= 1) {
            int x = (t >= off) ? s[t - off] : 0;
            __syncthreads();
            s[t] += x;
            __syncthreads();
        }
        const int total = s[SB - 1];
        if (i < nb) bsum[i] = carry + s[t] - v;
        carry += total;
        __syncthreads();
    }
    if (t == 0) ptr[N] = E;
}

__global__ __launch_bounds__(SB) void scanC_kernel(
    int* __restrict__ ptr, int* __restrict__ head,
    const int* __restrict__ bsum, int N)
{
    const int i = blockIdx.x * SB + threadIdx.x;
    if (i < N) {
        const int p = ptr[i] + bsum[blockIdx.x];
        ptr[i] = p;
        head[i] = p;
    }
}

// fill: ONLY 8B random write per edge (everything else gathered in agg3)
__global__ __launch_bounds__(256) void fill3_kernel(
    const int* __restrict__ ei, int* __restrict__ head,
    int2* __restrict__ pairs, int E)
{
    for (int e = blockIdx.x * blockDim.x + threadIdx.x; e < E;
         e += gridDim.x * blockDim.x) {
        const int t = ei[E + e];
        const int pos = atomicAdd(&head[t], 1);
        pairs[pos] = make_int2(e, ei[e]);
    }
}

// ---------------------------------------------------------------------------
// Node-per-wave fused MFMA projection + packed gather + PLAIN-STORE output.
// Wave grid-strides over nodes; per node, CSR slots [ptr[n],ptr[n+1]) are
// processed in 16-edge chunks through MFMA -> wave-private LDS P slice ->
// serial phase-3 with 1-deep pipelined pk/ev gathers. Accumulators carry
// across chunks; one plain store per node (covers ALL rows -> no memset).
// ---------------------------------------------------------------------------
__global__ __launch_bounds__(256, 6) void agg3_kernel(
    const unsigned int* __restrict__ pk,   // [N,192] packed bf16 (fw|vf)
    const ushort* __restrict__ radB,       // [E,32] bf16, EDGE order
    const float*  __restrict__ ev,         // [E,3]  edge order
    const float*  __restrict__ Wr,         // [32,192]
    const float*  __restrict__ br,         // [192]
    const int*    __restrict__ ptr,        // [N+1] CSR offsets
    const int2*   __restrict__ pairs,      // [E] (edge,src) CSR-sorted by tgt
    float* __restrict__ out_s,             // [N,64]
    float* __restrict__ out_v,             // [N,3,64]
    int N)
{
    __shared__ __align__(16) ushort Pl[4][16 * 200];   // 400B rows, per-wave

    const int tid  = threadIdx.x;
    const int lane = tid & 63;
    const int w    = tid >> 6;
    const int mr   = lane & 15;
    const int kk   = (lane >> 4) * 8;       // k offset in bf16 elems
    const int gwave  = blockIdx.x * 4 + w;
    const int nwaves = gridDim.x * 4;

    // B fragments (Wr) in registers: 12 tiles x 4 VGPRs
    short8 bfr[12];
    #pragma unroll
    for (int nt = 0; nt < 12; ++nt) {
        short8 b;
        #pragma unroll
        for (int j = 0; j < 8; ++j)
            b[j] = (short)bf16u(Wr[(kk + j) * 192 + nt * 16 + mr]);
        bfr[nt] = b;
    }
    const float b1 = br[lane], b2 = br[64 + lane], b3 = br[128 + lane];
    ushort* Pw = Pl[w];

    for (int n = gwave; n < N; n += nwaves) {
        const int s0 = ptr[n];
        const int s1 = ptr[n + 1];

        float as = 0.f, ax = 0.f, ay = 0.f, az = 0.f;

        for (int base = s0; base < s1; base += 16) {
            const int m = min(16, s1 - base);
            const int idx = min(base + mr, s1 - 1);

            const int2 pr = pairs[idx];          // coalesced 8B (lanes 0..15 x4)
            const int e_v = pr.x;
            const int s_v = pr.y;

            // A fragment: random 64B row of pre-converted bf16 rad
            short8 a0 = *(const short8*)(radB + (size_t)e_v * RR + kk);

            // MFMA: P[16][192] = A[16][32] @ Wr[32][192] -> bf16 LDS (swizzled)
            #pragma unroll
            for (int nt = 0; nt < 12; ++nt) {
                f32x4 c0 = {0.f, 0.f, 0.f, 0.f};
                c0 = __builtin_amdgcn_mfma_f32_16x16x32_bf16(a0, bfr[nt], c0, 0, 0, 0);
                #pragma unroll
                for (int r = 0; r < 4; ++r) {
                    const int row = ((lane >> 4) << 2) + r;   // C: row=(lane>>4)*4+reg
                    *(ushort*)((char*)Pw + row * 400 +
                               ((nt * 32 + mr * 2) ^ ((row & 12) << 3))) = bf16u(c0[r]);
                }
            }

            // --- phase 3: serial sweep, 1-deep pipelined gathers ---
            {
                int ec = rdlane_i(e_v, 0);
                int sc = rdlane_i(s_v, 0);
                const unsigned int* pp = pk + (size_t)sc * 192;
                unsigned int u1 = pp[lane], u2 = pp[64 + lane], u3 = pp[128 + lane];
                float ex = ev[3 * (size_t)ec + 0];
                float ey = ev[3 * (size_t)ec + 1];
                float ez = ev[3 * (size_t)ec + 2];

                for (int i = 0; i < m; ++i) {
                    const int inext = min(i + 1, m - 1);
                    const int en = rdlane_i(e_v, inext);
                    const int sn = rdlane_i(s_v, inext);
                    const unsigned int* ppn = pk + (size_t)sn * 192;
                    const unsigned int n1 = ppn[lane];
                    const unsigned int n2 = ppn[64 + lane];
                    const unsigned int n3 = ppn[128 + lane];
                    const float nex = ev[3 * (size_t)en + 0];
                    const float ney = ev[3 * (size_t)en + 1];
                    const float nez = ev[3 * (size_t)en + 2];

                    const int swz = (i & 12) << 3;
                    const char* prow = (const char*)Pw + i * 400;
                    ushort q1 = *(const ushort*)(prow + ((lane * 2) ^ swz));
                    ushort q2 = *(const ushort*)(prow + (((64 + lane) * 2) ^ swz));
                    ushort q3 = *(const ushort*)(prow + (((128 + lane) * 2) ^ swz));
                    const float p1 = __uint_as_float((unsigned int)q1 << 16) + b1;
                    const float p2 = __uint_as_float((unsigned int)q2 << 16) + b2;
                    const float p3 = __uint_as_float((unsigned int)q3 << 16) + b3;

                    const float f1 = __uint_as_float(u1 & 0xFFFF0000u);
                    const float f2 = __uint_as_float(u2 & 0xFFFF0000u);
                    const float f3 = __uint_as_float(u3 & 0xFFFF0000u);
                    const float v1 = __uint_as_float(u1 << 16);
                    const float v2 = __uint_as_float(u2 << 16);
                    const float v3 = __uint_as_float(u3 << 16);

                    const float cc1 = f1 * p1 * INV_SQRT_3;
                    const float cc2 = f2 * p2 * INV_SQRT_3;
                    const float cc3 = f3 * p3 * INV_SQRT_3;

                    as += cc3;
                    ax = fmaf(cc1, v1, fmaf(cc2, ex, ax));
                    ay = fmaf(cc1, v2, fmaf(cc2, ey, ay));
                    az = fmaf(cc1, v3, fmaf(cc2, ez, az));

                    u1 = n1; u2 = n2; u3 = n3;
                    ex = nex; ey = ney; ez = nez;
                }
            }
        }

        // plain stores (no atomics); every node row is written
        out_s[(size_t)n * 64 + lane]        = as;
        out_v[(size_t)n * 192 + lane]       = ax * INV_SQRT_H;
        out_v[(size_t)n * 192 + 64 + lane]  = ay * INV_SQRT_H;
        out_v[(size_t)n * 192 + 128 + lane] = az * INV_SQRT_H;
    }
}

// ---------------------------------------------------------------------------
// Fallback (atomic scatter) if ws can't hold scratch; uses packed table.
// ---------------------------------------------------------------------------
__global__ __launch_bounds__(256) void edge_kernel_atomic(
    const unsigned int* __restrict__ pk, const int* __restrict__ ei,
    const float* __restrict__ rad, const float* __restrict__ ev,
    const float* __restrict__ Wr, const float* __restrict__ br,
    float* __restrict__ out_s, float* __restrict__ out_v, int E)
{
    const int lane = threadIdx.x & 63;
    const int wid  = __builtin_amdgcn_readfirstlane((int)(threadIdx.x >> 6));
    const int wavesPerBlock = blockDim.x >> 6;
    const int totalWaves = gridDim.x * wavesPerBlock;
    const int w0 = blockIdx.x * wavesPerBlock + wid;

    float c1[RR], c2[RR], c3[RR];
    #pragma unroll
    for (int r = 0; r < RR; ++r) {
        c1[r] = Wr[r * 192 + lane];
        c2[r] = Wr[r * 192 + 64 + lane];
        c3[r] = Wr[r * 192 + 128 + lane];
    }
    const float b1 = br[lane], b2 = br[64 + lane], b3 = br[128 + lane];

    for (int e = w0; e < E; e += totalWaves) {
        const int eu  = __builtin_amdgcn_readfirstlane(e);
        const int src = ei[eu];
        const int tgt = ei[E + eu];

        const float* rp = rad + (size_t)eu * RR;
        float w1 = b1, w2 = b2, w3 = b3;
        #pragma unroll
        for (int r = 0; r < RR; ++r) {
            const float rv = rp[r];
            w1 = fmaf(rv, c1[r], w1);
            w2 = fmaf(rv, c2[r], w2);
            w3 = fmaf(rv, c3[r], w3);
        }

        const float evx = ev[eu * 3 + 0];
        const float evy = ev[eu * 3 + 1];
        const float evz = ev[eu * 3 + 2];

        const unsigned int* pp = pk + (size_t)src * 192;
        const unsigned int u1 = pp[lane], u2 = pp[64 + lane], u3 = pp[128 + lane];
        const float f1 = __uint_as_float(u1 & 0xFFFF0000u);
        const float f2 = __uint_as_float(u2 & 0xFFFF0000u);
        const float f3 = __uint_as_float(u3 & 0xFFFF0000u);
        const float v1 = __uint_as_float(u1 << 16);
        const float v2 = __uint_as_float(u2 << 16);
        const float v3 = __uint_as_float(u3 << 16);

        const float cc1 = f1 * w1 * INV_SQRT_3;
        const float cc2 = f2 * w2 * INV_SQRT_3;
        const float cc3 = f3 * w3 * INV_SQRT_3;

        unsafeAtomicAdd(&out_s[(size_t)tgt * 64 + lane], cc3);
        unsafeAtomicAdd(&out_v[(size_t)tgt * 192 + lane],
                        (cc1 * v1 + cc2 * evx) * INV_SQRT_H);
        unsafeAtomicAdd(&out_v[(size_t)tgt * 192 + 64 + lane],
                        (cc1 * v2 + cc2 * evy) * INV_SQRT_H);
        unsafeAtomicAdd(&out_v[(size_t)tgt * 192 + 128 + lane],
                        (cc1 * v3 + cc2 * evz) * INV_SQRT_H);
    }
}

extern "C" void kernel_launch(void* const* d_in, const int* in_sizes, int n_in,
                              void* d_out, int out_size, void* d_ws, size_t ws_size,
                              hipStream_t stream) {
    const float* nf  = (const float*)d_in[0];
    const float* vf  = (const float*)d_in[1];
    const int*   ei  = (const int*)  d_in[2];
    const float* rad = (const float*)d_in[3];
    const float* ev  = (const float*)d_in[4];
    const float* Wf1 = (const float*)d_in[5];
    const float* bf1 = (const float*)d_in[6];
    const float* Wf2 = (const float*)d_in[7];
    const float* bf2 = (const float*)d_in[8];
    const float* Wr  = (const float*)d_in[9];
    const float* br  = (const float*)d_in[10];

    const int N = in_sizes[0] / HH;
    const int E = in_sizes[2] / 2;
    const int nb = (N + SB - 1) / SB;

    float* out_s = (float*)d_out;                // [N,64]
    float* out_v = out_s + (size_t)N * HH;       // [N,3,64]

    // ws layout
    char* ws = (char*)d_ws;
    size_t off = 0;
    unsigned int* pkt = (unsigned int*)(ws + off); off += (size_t)N * 192 * 4;
    int* cnt  = (int*)(ws + off);     off += (size_t)N * 4;
    int* ptr  = (int*)(ws + off);     off += (size_t)(N + 1) * 4;
    int* head = (int*)(ws + off);     off += (size_t)N * 4;
    int* bsum = (int*)(ws + off);     off += (size_t)nb * 4;
    off = (off + 15) & ~(size_t)15;
    ushort* radB = (ushort*)(ws + off); off += (size_t)E * RR * 2;
    off = (off + 15) & ~(size_t)15;
    int2* pairs = (int2*)(ws + off);  off += (size_t)E * 8;

    const int fgrid = min(1280, (N + 7) / 8) > 0 ? min(1280, (N + 7) / 8) : 1;
    feat2_kernel<<<fgrid, 256, 0, stream>>>(nf, vf, Wf1, bf1, Wf2, bf2, pkt, N);

    if (off <= ws_size) {
        hipMemsetAsync(cnt, 0, (size_t)N * 4, stream);
        histconv_kernel<<<2048, 256, 0, stream>>>(ei, rad, cnt, radB, E);
        scanA_kernel<<<nb, SB, 0, stream>>>(cnt, ptr, bsum, N);
        scanB_kernel<<<1, SB, 0, stream>>>(bsum, nb, ptr, N, E);
        scanC_kernel<<<nb, SB, 0, stream>>>(ptr, head, bsum, N);
        fill3_kernel<<<2048, 256, 0, stream>>>(ei, head, pairs, E);

        // node-per-wave aggregation: writes EVERY output row -> no memset
        agg3_kernel<<<1536, 256, 0, stream>>>(pkt, radB, ev, Wr, br,
                                              ptr, pairs, out_s, out_v, N);
    } else {
        hipMemsetAsync(d_out, 0, (size_t)out_size * sizeof(float), stream);
        edge_kernel_atomic<<<2048, 256, 0, stream>>>(pkt, ei, rad, ev, Wr, br,
                                                     out_s, out_v, E);
    }
}

// Round 9
// 346.812 us; speedup vs baseline: 2.3156x; 1.0262x over previous
//
#include <hip/hip_runtime.h>
#include <hip/hip_bf16.h>

#define HH 64
#define RR 32
#define SILU_SCALE (1.0f / 0.6f)
#define INV_SQRT_3 0.57735026918962576f
#define INV_SQRT_H 0.125f   // 1/sqrt(64)
#define SB 256              // scan block size

typedef __attribute__((ext_vector_type(8))) short short8;
typedef __attribute__((ext_vector_type(4))) float f32x4;

__device__ __forceinline__ int rdlane_i(int v, int l) {
    return __builtin_amdgcn_readlane(v, l);
}
__device__ __forceinline__ ushort bf16u(float x) {
    __hip_bfloat16 h = __float2bfloat16(x);
    return *(ushort*)&h;
}
__device__ __forceinline__ float bf16f(ushort u) {
    return __uint_as_float((unsigned int)u << 16);
}

// ---------------------------------------------------------------------------
// Kernel 1: feat_w -> packed table pk[n][c] = (bf16(fw)<<16)|bf16(vf).
// Also zeroes cnt[] for the histogram (verified rounds 7/8).
// ---------------------------------------------------------------------------
__global__ __launch_bounds__(256) void feat2_kernel(
    const float* __restrict__ nf,
    const float* __restrict__ vf,
    const float* __restrict__ Wf1, const float* __restrict__ bf1,
    const float* __restrict__ Wf2, const float* __restrict__ bf2,
    unsigned int* __restrict__ pk, int* __restrict__ cnt, int N)
{
    __shared__ float sW1[64 * 32];
    __shared__ float sW2[32 * 192];
    __shared__ float sb1[32];
    __shared__ float sb2[192];
    __shared__ float snf[8 * 66];   // 64 + 2 pad
    __shared__ float sh[8 * 34];    // 32 + 2 pad

    const int tid = threadIdx.x;
    for (int i = blockIdx.x * 256 + tid; i < N; i += gridDim.x * 256) cnt[i] = 0;

    for (int i = tid; i < 64 * 32; i += 256) sW1[i] = Wf1[i];
    for (int i = tid; i < 32 * 192; i += 256) sW2[i] = Wf2[i];
    if (tid < 32) sb1[tid] = bf1[tid];
    if (tid < 192) sb2[tid] = bf2[tid];
    __syncthreads();

    const int sub = tid >> 5;
    const int l32 = tid & 31;

    for (int n0 = blockIdx.x * 8; n0 < N; n0 += gridDim.x * 8) {
        const int nrem = min(8, N - n0);
        for (int i = tid; i < nrem * 64; i += 256)
            snf[(i >> 6) * 66 + (i & 63)] = nf[(size_t)n0 * 64 + i];
        __syncthreads();

        const int n = n0 + sub;
        {
            float a = sb1[l32];
            const float* x = &snf[sub * 66];
            #pragma unroll
            for (int i = 0; i < 64; ++i)
                a = fmaf(x[i], sW1[i * 32 + l32], a);
            sh[sub * 34 + l32] = a / (1.0f + __expf(-a)) * SILU_SCALE;
        }
        // sh written/read within the same 32-lane group -> no barrier
        if (n < N) {
            #pragma unroll
            for (int k = 0; k < 6; ++k) {
                const int col = l32 + 32 * k;
                const float vvf = vf[(size_t)n * 192 + col];
                float o = sb2[col];
                #pragma unroll
                for (int j = 0; j < 32; ++j)
                    o = fmaf(sh[sub * 34 + j], sW2[j * 192 + col], o);
                pk[(size_t)n * 192 + col] =
                    ((unsigned int)bf16u(o) << 16) | (unsigned int)bf16u(vvf);
            }
        }
        __syncthreads();
    }
}

// ---------------------------------------------------------------------------
// Counting sort by target: hist -> scan -> fill (pairs only: 8B/edge random)
// ---------------------------------------------------------------------------
__global__ __launch_bounds__(256) void hist_kernel(
    const int* __restrict__ ei, int* __restrict__ cnt, int E)
{
    for (int e = blockIdx.x * blockDim.x + threadIdx.x; e < E;
         e += gridDim.x * blockDim.x)
        atomicAdd(&cnt[ei[E + e]], 1);
}

__global__ __launch_bounds__(SB) void scanA_kernel(
    const int* __restrict__ cnt, int* __restrict__ ptr,
    int* __restrict__ bsum, int N)
{
    __shared__ int s[SB];
    const int t = threadIdx.x;
    const int i = blockIdx.x * SB + t;
    const int v = (i < N) ? cnt[i] : 0;
    s[t] = v; __syncthreads();
    for (int off = 1; off < SB; off <<= 1) {
        int x = (t >= off) ? s[t - off] : 0;
        __syncthreads();
        s[t] += x;
        __syncthreads();
    }
    if (i < N) ptr[i] = s[t] - v;
    if (t == SB - 1) bsum[blockIdx.x] = s[t];
}

__global__ __launch_bounds__(SB) void scanB_kernel(
    int* __restrict__ bsum, int nb, int* __restrict__ ptr, int N, int E)
{
    __shared__ int s[SB];
    const int t = threadIdx.x;
    int carry = 0;
    for (int base = 0; base < nb; base += SB) {
        const int i = base + t;
        const int v = (i < nb) ? bsum[i] : 0;
        s[t] = v; __syncthreads();
        for (int off = 1; off < SB; off <<= 1) {
            int x = (t >= off) ? s[t - off] : 0;
            __syncthreads();
            s[t] += x;
            __syncthreads();
        }
        const int total = s[SB - 1];
        if (i < nb) bsum[i] = carry + s[t] - v;
        carry += total;
        __syncthreads();
    }
    if (t == 0) ptr[N] = E;
}

__global__ __launch_bounds__(SB) void scanC_kernel(
    int* __restrict__ ptr, int* __restrict__ head,
    const int* __restrict__ bsum, int N)
{
    const int i = blockIdx.x * SB + threadIdx.x;
    if (i < N) {
        const int p = ptr[i] + bsum[blockIdx.x];
        ptr[i] = p;
        head[i] = p;
    }
}

__global__ __launch_bounds__(256) void fill3_kernel(
    const int* __restrict__ ei, int* __restrict__ head,
    int2* __restrict__ pairs, int E)
{
    for (int e = blockIdx.x * blockDim.x + threadIdx.x; e < E;
         e += gridDim.x * blockDim.x) {
        const int t = ei[E + e];
        const int pos = atomicAdd(&head[t], 1);
        pairs[pos] = make_int2(e, ei[e]);
    }
}

// ---------------------------------------------------------------------------
// agg6: round-6 agg3 VERBATIM (passed, absmax 0.125) with ONE change: the
// A-fragment is built from f32 rad with in-kernel bf16 conversion (this exact
// conversion was verified by rounds 7/8's passing scalar output), removing
// the radB pre-conversion pass entirely.
// Node-per-wave; MFMA -> per-wave swizzled LDS P slice; serial phase 3 with
// 1-deep pipelined pk/ev gathers; plain stores (no atomics, no memset).
// ---------------------------------------------------------------------------
__global__ __launch_bounds__(256, 6) void agg6_kernel(
    const unsigned int* __restrict__ pk,   // [N,192] packed bf16 (fw|vf)
    const float* __restrict__ rad,         // [E,32] f32, edge order
    const float* __restrict__ ev,          // [E,3]  edge order
    const float* __restrict__ Wr,          // [32,192]
    const float* __restrict__ br,          // [192]
    const int*  __restrict__ ptr,          // [N+1] CSR offsets
    const int2* __restrict__ pairs,        // [E] (edge,src) sorted by tgt
    float* __restrict__ out_s,             // [N,64]
    float* __restrict__ out_v,             // [N,3,64]
    int N)
{
    __shared__ __align__(16) ushort Pl[4][16 * 200];   // 400B rows, per-wave

    const int tid  = threadIdx.x;
    const int lane = tid & 63;
    const int w    = tid >> 6;
    const int mr   = lane & 15;
    const int kk   = (lane >> 4) * 8;       // k offset in bf16 elems
    const int gwave  = blockIdx.x * 4 + w;
    const int nwaves = gridDim.x * 4;

    // B fragments (Wr) in registers: 12 tiles x 4 VGPRs (round-6 verbatim)
    short8 bfr[12];
    #pragma unroll
    for (int nt = 0; nt < 12; ++nt) {
        short8 b;
        #pragma unroll
        for (int j = 0; j < 8; ++j)
            b[j] = (short)bf16u(Wr[(kk + j) * 192 + nt * 16 + mr]);
        bfr[nt] = b;
    }
    const float b1 = br[lane], b2 = br[64 + lane], b3 = br[128 + lane];
    ushort* Pw = Pl[w];

    for (int n = gwave; n < N; n += nwaves) {
        const int s0 = ptr[n];
        const int s1 = ptr[n + 1];

        float as = 0.f, ax = 0.f, ay = 0.f, az = 0.f;

        for (int base = s0; base < s1; base += 16) {
            const int m = min(16, s1 - base);
            const int idx = min(base + mr, s1 - 1);

            const int2 pr = pairs[idx];          // coalesced 8B
            const int e_v = pr.x;
            const int s_v = pr.y;

            // A fragment from f32 rad row (verified by r7/r8 scalar output)
            const float* rp = rad + (size_t)e_v * RR + kk;
            const float4 ra = *(const float4*)rp;
            const float4 rb = *(const float4*)(rp + 4);
            short8 a0;
            a0[0] = (short)bf16u(ra.x); a0[1] = (short)bf16u(ra.y);
            a0[2] = (short)bf16u(ra.z); a0[3] = (short)bf16u(ra.w);
            a0[4] = (short)bf16u(rb.x); a0[5] = (short)bf16u(rb.y);
            a0[6] = (short)bf16u(rb.z); a0[7] = (short)bf16u(rb.w);

            // MFMA: P[16][192] = A[16][32] @ Wr[32][192] -> bf16 LDS (swizzled)
            #pragma unroll
            for (int nt = 0; nt < 12; ++nt) {
                f32x4 c0 = {0.f, 0.f, 0.f, 0.f};
                c0 = __builtin_amdgcn_mfma_f32_16x16x32_bf16(a0, bfr[nt], c0, 0, 0, 0);
                #pragma unroll
                for (int r = 0; r < 4; ++r) {
                    const int row = ((lane >> 4) << 2) + r;   // C: row=(lane>>4)*4+reg
                    *(ushort*)((char*)Pw + row * 400 +
                               ((nt * 32 + mr * 2) ^ ((row & 12) << 3))) = bf16u(c0[r]);
                }
            }

            // --- phase 3: serial sweep, 1-deep pipelined gathers (r6 verbatim) ---
            {
                int ec = rdlane_i(e_v, 0);
                int sc = rdlane_i(s_v, 0);
                const unsigned int* pp = pk + (size_t)sc * 192;
                unsigned int u1 = pp[lane], u2 = pp[64 + lane], u3 = pp[128 + lane];
                float ex = ev[3 * (size_t)ec + 0];
                float ey = ev[3 * (size_t)ec + 1];
                float ez = ev[3 * (size_t)ec + 2];

                for (int i = 0; i < m; ++i) {
                    const int inext = min(i + 1, m - 1);
                    const int en = rdlane_i(e_v, inext);
                    const int sn = rdlane_i(s_v, inext);
                    const unsigned int* ppn = pk + (size_t)sn * 192;
                    const unsigned int n1 = ppn[lane];
                    const unsigned int n2 = ppn[64 + lane];
                    const unsigned int n3 = ppn[128 + lane];
                    const float nex = ev[3 * (size_t)en + 0];
                    const float ney = ev[3 * (size_t)en + 1];
                    const float nez = ev[3 * (size_t)en + 2];

                    const int swz = (i & 12) << 3;
                    const char* prow = (const char*)Pw + i * 400;
                    ushort q1 = *(const ushort*)(prow + ((lane * 2) ^ swz));
                    ushort q2 = *(const ushort*)(prow + (((64 + lane) * 2) ^ swz));
                    ushort q3 = *(const ushort*)(prow + (((128 + lane) * 2) ^ swz));
                    const float p1 = bf16f(q1) + b1;
                    const float p2 = bf16f(q2) + b2;
                    const float p3 = bf16f(q3) + b3;

                    const float f1 = __uint_as_float(u1 & 0xFFFF0000u);
                    const float f2 = __uint_as_float(u2 & 0xFFFF0000u);
                    const float f3 = __uint_as_float(u3 & 0xFFFF0000u);
                    const float v1 = __uint_as_float(u1 << 16);
                    const float v2 = __uint_as_float(u2 << 16);
                    const float v3 = __uint_as_float(u3 << 16);

                    const float cc1 = f1 * p1 * INV_SQRT_3;
                    const float cc2 = f2 * p2 * INV_SQRT_3;
                    const float cc3 = f3 * p3 * INV_SQRT_3;

                    as += cc3;
                    ax = fmaf(cc1, v1, fmaf(cc2, ex, ax));
                    ay = fmaf(cc1, v2, fmaf(cc2, ey, ay));
                    az = fmaf(cc1, v3, fmaf(cc2, ez, az));

                    u1 = n1; u2 = n2; u3 = n3;
                    ex = nex; ey = ney; ez = nez;
                }
            }
        }

        // plain stores (no atomics); every node row is written
        out_s[(size_t)n * 64 + lane]        = as;
        out_v[(size_t)n * 192 + lane]       = ax * INV_SQRT_H;
        out_v[(size_t)n * 192 + 64 + lane]  = ay * INV_SQRT_H;
        out_v[(size_t)n * 192 + 128 + lane] = az * INV_SQRT_H;
    }
}

// ---------------------------------------------------------------------------
// Fallback (atomic scatter) if ws can't hold scratch; uses packed table.
// ---------------------------------------------------------------------------
__global__ __launch_bounds__(256) void edge_kernel_atomic(
    const unsigned int* __restrict__ pk, const int* __restrict__ ei,
    const float* __restrict__ rad, const float* __restrict__ ev,
    const float* __restrict__ Wr, const float* __restrict__ br,
    float* __restrict__ out_s, float* __restrict__ out_v, int E)
{
    const int lane = threadIdx.x & 63;
    const int wid  = __builtin_amdgcn_readfirstlane((int)(threadIdx.x >> 6));
    const int wavesPerBlock = blockDim.x >> 6;
    const int totalWaves = gridDim.x * wavesPerBlock;
    const int w0 = blockIdx.x * wavesPerBlock + wid;

    float c1[RR], c2[RR], c3[RR];
    #pragma unroll
    for (int r = 0; r < RR; ++r) {
        c1[r] = Wr[r * 192 + lane];
        c2[r] = Wr[r * 192 + 64 + lane];
        c3[r] = Wr[r * 192 + 128 + lane];
    }
    const float b1 = br[lane], b2 = br[64 + lane], b3 = br[128 + lane];

    for (int e = w0; e < E; e += totalWaves) {
        const int eu  = __builtin_amdgcn_readfirstlane(e);
        const int src = ei[eu];
        const int tgt = ei[E + eu];

        const float* rp = rad + (size_t)eu * RR;
        float w1 = b1, w2 = b2, w3 = b3;
        #pragma unroll
        for (int r = 0; r < RR; ++r) {
            const float rv = rp[r];
            w1 = fmaf(rv, c1[r], w1);
            w2 = fmaf(rv, c2[r], w2);
            w3 = fmaf(rv, c3[r], w3);
        }

        const float evx = ev[eu * 3 + 0];
        const float evy = ev[eu * 3 + 1];
        const float evz = ev[eu * 3 + 2];

        const unsigned int* pp = pk + (size_t)src * 192;
        const unsigned int u1 = pp[lane], u2 = pp[64 + lane], u3 = pp[128 + lane];
        const float f1 = __uint_as_float(u1 & 0xFFFF0000u);
        const float f2 = __uint_as_float(u2 & 0xFFFF0000u);
        const float f3 = __uint_as_float(u3 & 0xFFFF0000u);
        const float v1 = __uint_as_float(u1 << 16);
        const float v2 = __uint_as_float(u2 << 16);
        const float v3 = __uint_as_float(u3 << 16);

        const float cc1 = f1 * w1 * INV_SQRT_3;
        const float cc2 = f2 * w2 * INV_SQRT_3;
        const float cc3 = f3 * w3 * INV_SQRT_3;

        unsafeAtomicAdd(&out_s[(size_t)tgt * 64 + lane], cc3);
        unsafeAtomicAdd(&out_v[(size_t)tgt * 192 + lane],
                        (cc1 * v1 + cc2 * evx) * INV_SQRT_H);
        unsafeAtomicAdd(&out_v[(size_t)tgt * 192 + 64 + lane],
                        (cc1 * v2 + cc2 * evy) * INV_SQRT_H);
        unsafeAtomicAdd(&out_v[(size_t)tgt * 192 + 128 + lane],
                        (cc1 * v3 + cc2 * evz) * INV_SQRT_H);
    }
}

extern "C" void kernel_launch(void* const* d_in, const int* in_sizes, int n_in,
                              void* d_out, int out_size, void* d_ws, size_t ws_size,
                              hipStream_t stream) {
    const float* nf  = (const float*)d_in[0];
    const float* vf  = (const float*)d_in[1];
    const int*   ei  = (const int*)  d_in[2];
    const float* rad = (const float*)d_in[3];
    const float* ev  = (const float*)d_in[4];
    const float* Wf1 = (const float*)d_in[5];
    const float* bf1 = (const float*)d_in[6];
    const float* Wf2 = (const float*)d_in[7];
    const float* bf2 = (const float*)d_in[8];
    const float* Wr  = (const float*)d_in[9];
    const float* br  = (const float*)d_in[10];

    const int N = in_sizes[0] / HH;
    const int E = in_sizes[2] / 2;
    const int nb = (N + SB - 1) / SB;

    float* out_s = (float*)d_out;                // [N,64]
    float* out_v = out_s + (size_t)N * HH;       // [N,3,64]

    // ws layout
    char* ws = (char*)d_ws;
    size_t off = 0;
    unsigned int* pkt = (unsigned int*)(ws + off); off += (size_t)N * 192 * 4;
    int* cnt  = (int*)(ws + off);     off += (size_t)N * 4;
    int* ptr  = (int*)(ws + off);     off += (size_t)(N + 1) * 4;
    int* head = (int*)(ws + off);     off += (size_t)N * 4;
    int* bsum = (int*)(ws + off);     off += (size_t)nb * 4;
    off = (off + 15) & ~(size_t)15;
    int2* pairs = (int2*)(ws + off);  off += (size_t)E * 8;

    const int fgrid = min(1280, (N + 7) / 8) > 0 ? min(1280, (N + 7) / 8) : 1;
    feat2_kernel<<<fgrid, 256, 0, stream>>>(nf, vf, Wf1, bf1, Wf2, bf2,
                                            pkt, cnt, N);

    if (off <= ws_size) {
        hist_kernel<<<2048, 256, 0, stream>>>(ei, cnt, E);
        scanA_kernel<<<nb, SB, 0, stream>>>(cnt, ptr, bsum, N);
        scanB_kernel<<<1, SB, 0, stream>>>(bsum, nb, ptr, N, E);
        scanC_kernel<<<nb, SB, 0, stream>>>(ptr, head, bsum, N);
        fill3_kernel<<<2048, 256, 0, stream>>>(ei, head, pairs, E);

        // node-per-wave aggregation: writes EVERY output row -> no memset
        agg6_kernel<<<1536, 256, 0, stream>>>(pkt, rad, ev, Wr, br,
                                              ptr, pairs, out_s, out_v, N);
    } else {
        hipMemsetAsync(d_out, 0, (size_t)out_size * sizeof(float), stream);
        edge_kernel_atomic<<<2048, 256, 0, stream>>>(pkt, ei, rad, ev, Wr, br,
                                                     out_s, out_v, E);
    }
}